// Round 4
// baseline (3763.483 us; speedup 1.0000x reference)
//
#include <hip/hip_runtime.h>
#include <hip/hip_bf16.h>

#define N_USERS 70000
#define N_ITEMS 30000
#define N_NODES 100000
#define RD 192      // R*D
#define EE 1600000
#define NE3 4800000
#define M3 300000   // 3 * N_NODES counts

// output element offsets (dtype-independent)
#define OFF_U    0
#define OFF_I    13440000
#define OFF_IZ   19200000   // zero row (item index 30000)
#define OFF_RELA 19200192
#define OFF_S1   19200384
#define OFF_S2   19270384

typedef __hip_bfloat16 bf16;

__device__ __forceinline__ float b2f(bf16 v) { return __bfloat162float(v); }

// dtype-adaptive IO: f32 -> fp32 arrays, else bf16 arrays
__device__ __forceinline__ float loadf(const void* p, int i, bool f32) {
  return f32 ? ((const float*)p)[i] : b2f(((const bf16*)p)[i]);
}
__device__ __forceinline__ void storef(void* p, int i, float v, bool f32) {
  if (f32) ((float*)p)[i] = v;
  else ((bf16*)p)[i] = __float2bfloat16(v);
}

__device__ __forceinline__ float wave_sum(float v) {
#pragma unroll
  for (int off = 32; off >= 1; off >>= 1) v += __shfl_xor(v, off, 64);
  return v;
}

__global__ void detect_kernel(const unsigned short* __restrict__ ue,
                              int* __restrict__ flag) {
  __shared__ int s;
  int t = threadIdx.x;
  if (t == 0) s = 0;
  __syncthreads();
  int big = 0;
  for (int j = t; j < 8192; j += 256) {
    int e = (ue[j] >> 7) & 0xFF;
    if (e >= 127) big = 1;
  }
  if (big) atomicOr(&s, 1);
  __syncthreads();
  if (t == 0) *flag = s;
}

__global__ void zero_row_kernel(void* out, const int* __restrict__ flag) {
  bool f32 = *flag != 0;
  storef(out, OFF_IZ + (int)threadIdx.x, 0.f, f32);  // 192 threads
}

// rela chain: rela0=rel_emb, rela1=rela0@W_rel[0], rela2=rela1@W_rel[1]
__global__ void rela_kernel(const void* __restrict__ rel_emb,
                            const void* __restrict__ W_rel,
                            const int* __restrict__ flag,
                            float* __restrict__ rela_f, void* out) {
  bool f32 = *flag != 0;
  __shared__ float r0s[192], r1s[192];
  int t = threadIdx.x;            // 192 threads
  int i = t >> 6, d = t & 63;
  float r0 = loadf(rel_emb, t, f32);
  r0s[t] = r0;
  __syncthreads();
  float acc = 0.f;
  for (int k = 0; k < 64; ++k)
    acc += r0s[i * 64 + k] * loadf(W_rel, k * 64 + d, f32);
  r1s[t] = acc;
  __syncthreads();
  float acc2 = 0.f;
  for (int k = 0; k < 64; ++k)
    acc2 += r1s[i * 64 + k] * loadf(W_rel, 4096 + k * 64 + d, f32);
  rela_f[t] = r0;
  rela_f[192 + t] = acc;
  rela_f[384 + t] = acc2;
  storef(out, OFF_RELA + t, (r0 + acc + acc2) * (1.f / 3.f), f32);
}

__global__ __launch_bounds__(256) void init_kernel(
    const void* __restrict__ user_emb, const void* __restrict__ item_emb,
    const int* __restrict__ flag, bf16* __restrict__ ego,
    float* __restrict__ all_emb) {
  bool f32 = *flag != 0;
  int idx = blockIdx.x * 256 + threadIdx.x;
  if (idx >= N_NODES * RD) return;
  int n = idx / RD;
  int rd = idx - n * RD;
  int d = rd & 63;
  float v = (n < N_USERS) ? loadf(user_emb, n * 64 + d, f32)
                          : loadf(item_emb, (n - N_USERS) * 64 + d, f32);
  ego[idx] = __float2bfloat16(v);
  all_emb[idx] = v;
}

// ---- CSR build ----
__global__ __launch_bounds__(256) void hist_kernel(
    const int* __restrict__ rows, int* __restrict__ counts) {
  int idx = blockIdx.x * 256 + threadIdx.x;
  if (idx >= NE3) return;
  int i = idx / EE;
  atomicAdd(counts + i * N_NODES + rows[idx], 1);
}

// block-level exclusive scan (1024/block), writes block totals
__global__ __launch_bounds__(1024) void scanA_kernel(
    const int* __restrict__ counts, int* __restrict__ offs,
    int* __restrict__ bsums) {
  __shared__ int s[1024];
  int t = threadIdx.x;
  int idx = blockIdx.x * 1024 + t;
  int x = (idx < M3) ? counts[idx] : 0;
  s[t] = x;
  __syncthreads();
  for (int off = 1; off < 1024; off <<= 1) {
    int y = (t >= off) ? s[t - off] : 0;
    __syncthreads();
    s[t] += y;
    __syncthreads();
  }
  if (idx < M3) offs[idx] = s[t] - x;
  if (t == 1023) bsums[blockIdx.x] = s[t];
}

__global__ __launch_bounds__(512) void scanB_kernel(
    const int* __restrict__ bsums, int* __restrict__ bsums2, int nb) {
  __shared__ int s[512];
  int t = threadIdx.x;
  int x = (t < nb) ? bsums[t] : 0;
  s[t] = x;
  __syncthreads();
  for (int off = 1; off < 512; off <<= 1) {
    int y = (t >= off) ? s[t - off] : 0;
    __syncthreads();
    s[t] += y;
    __syncthreads();
  }
  if (t < nb) bsums2[t] = s[t] - x;
}

__global__ __launch_bounds__(1024) void scanC_kernel(
    int* __restrict__ offs, const int* __restrict__ bsums2,
    int* __restrict__ cursors) {
  int idx = blockIdx.x * 1024 + threadIdx.x;
  if (idx >= M3) return;
  int v = offs[idx] + bsums2[blockIdx.x];
  offs[idx] = v;
  cursors[idx] = v;
}

__global__ __launch_bounds__(256) void reorder_kernel(
    const int* __restrict__ rows, const int* __restrict__ cols,
    const void* __restrict__ vals, const int* __restrict__ flag,
    int* __restrict__ cursors, int* __restrict__ scol,
    bf16* __restrict__ sval) {
  bool f32 = *flag != 0;
  int idx = blockIdx.x * 256 + threadIdx.x;
  if (idx >= NE3) return;
  int i = idx / EE;
  int r = rows[idx];
  float v = loadf(vals, idx, f32);
  int pos = atomicAdd(cursors + i * N_NODES + r, 1);
  scol[pos] = cols[idx];
  sval[pos] = __float2bfloat16(v);
}

__device__ __forceinline__ float attn_row(float a, float b, float c,
                                          float e0, float e1, float e2) {
  float m = fmaxf(a, fmaxf(b, c));
  float w0 = __expf(a - m), w1 = __expf(b - m), w2 = __expf(c - m);
  float inv = 1.f / (w0 + w1 + w2);
  return (w0 * e0 + w1 * e1 + w2 * e2) * inv;
}

// Fused gather + transform + attention. 8 nodes per wave, 32 per block.
__global__ __launch_bounds__(256) void gt_kernel(
    const int* __restrict__ scol, const bf16* __restrict__ sval,
    const int* __restrict__ counts, const int* __restrict__ offs,
    const float* __restrict__ rela_k, const void* __restrict__ Wgc,
    int wgc_off, const int* __restrict__ flag,
    const bf16* __restrict__ ego_prev, bf16* __restrict__ ego_next,
    float* __restrict__ all_emb) {
  bool f32 = *flag != 0;
  __shared__ float Ws[4096];
  int t = threadIdx.x, lane = t & 63, wave = t >> 6;
  for (int j = t; j < 4096; j += 256) Ws[j] = loadf(Wgc, wgc_off + j, f32);
  float rel0 = rela_k[lane], rel1 = rela_k[64 + lane], rel2 = rela_k[128 + lane];
  __syncthreads();
  const float sc = 0.088388347648318447f;  // 1/sqrt(128)
  for (int jj = 0; jj < 8; ++jj) {
    int n = blockIdx.x * 32 + wave * 8 + jj;
    float e[3];
#pragma unroll
    for (int i = 0; i < 3; ++i) {
      int base = offs[i * N_NODES + n];
      int cnt = counts[i * N_NODES + n];
      float a0 = 0.f, a1 = 0.f, a2 = 0.f, a3 = 0.f;
      int j = 0;
      for (; j + 4 <= cnt; j += 4) {
        int c0 = scol[base + j], c1 = scol[base + j + 1];
        int c2 = scol[base + j + 2], c3 = scol[base + j + 3];
        float v0 = b2f(sval[base + j]), v1 = b2f(sval[base + j + 1]);
        float v2 = b2f(sval[base + j + 2]), v3 = b2f(sval[base + j + 3]);
        a0 += b2f(ego_prev[c0 * RD + i * 64 + lane]) * v0;
        a1 += b2f(ego_prev[c1 * RD + i * 64 + lane]) * v1;
        a2 += b2f(ego_prev[c2 * RD + i * 64 + lane]) * v2;
        a3 += b2f(ego_prev[c3 * RD + i * 64 + lane]) * v3;
      }
      for (; j < cnt; ++j) {
        int c0 = scol[base + j];
        float v0 = b2f(sval[base + j]);
        a0 += b2f(ego_prev[c0 * RD + i * 64 + lane]) * v0;
      }
      float rel = (i == 0) ? rel0 : ((i == 1) ? rel1 : rel2);
      float x = (a0 + a1 + a2 + a3) * rel;
      float acc = 0.f;
#pragma unroll
      for (int d = 0; d < 64; ++d)
        acc += __shfl(x, d, 64) * Ws[d * 64 + lane];
      e[i] = acc > 0.f ? acc : 0.01f * acc;
    }
    float e0 = e[0], e1 = e[1], e2 = e[2];
    float s00 = wave_sum(e0 * e0);
    float s01 = wave_sum(e0 * e1);
    float s02 = wave_sum(e0 * e2);
    float s11 = wave_sum(e1 * e1);
    float s12 = wave_sum(e1 * e2);
    float s22 = wave_sum(e2 * e2);
    float o0 = attn_row(s00 * sc, s01 * sc, s02 * sc, e0, e1, e2);
    float o1 = attn_row(s01 * sc, s11 * sc, s12 * sc, e0, e1, e2);
    float o2 = attn_row(s02 * sc, s12 * sc, s22 * sc, e0, e1, e2);
    int base = n * RD + lane;
    ego_next[base] = __float2bfloat16(o0);
    ego_next[base + 64] = __float2bfloat16(o1);
    ego_next[base + 128] = __float2bfloat16(o2);
    all_emb[base] += o0;
    all_emb[base + 64] += o1;
    all_emb[base + 128] += o2;
  }
}

// final attention (row 2 only) + outputs; users also do GRU matvecs + scores
__global__ __launch_bounds__(256) void final_kernel(
    const float* __restrict__ all_emb, const void* __restrict__ gru_w,
    const void* __restrict__ gru_b, const void* __restrict__ tra,
    const int* __restrict__ flag, void* out) {
  bool f32 = *flag != 0;
  __shared__ float Wg[3 * 4096];
  __shared__ float bs[192];
  __shared__ float ts[256];
  int t = threadIdx.x, lane = t & 63, wave = t >> 6;
  for (int j = t; j < 12288; j += 256) Wg[j] = loadf(gru_w, j, f32);
  if (t < 192) bs[t] = loadf(gru_b, t, f32);
  ts[t] = loadf(tra, t, f32);
  __syncthreads();
  int n0 = blockIdx.x * 64 + wave * 16;
  for (int jj = 0; jj < 16; ++jj) {
    int n = n0 + jj;
    if (n >= N_NODES) break;
    float a0 = all_emb[n * RD + lane];
    float a1 = all_emb[n * RD + 64 + lane];
    float a2 = all_emb[n * RD + 128 + lane];
    float s20 = wave_sum(a2 * a0);
    float s21 = wave_sum(a2 * a1);
    float s22 = wave_sum(a2 * a2);
    float mid2 = attn_row(s20, s21, s22, a0, a1, a2);
    float f0 = a0 * (1.f / 3.f), f1 = a1 * (1.f / 3.f), f2 = mid2 * (1.f / 3.f);
    if (n < N_USERS) {
      int ob = OFF_U + n * RD + lane;
      storef(out, ob, f0, f32);
      storef(out, ob + 64, f1, f32);
      storef(out, ob + 128, f2, f32);
      float y0 = bs[lane], y1 = bs[64 + lane], y2 = bs[128 + lane];
#pragma unroll
      for (int d = 0; d < 64; ++d) {
        y0 += __shfl(f0, d, 64) * Wg[d * 64 + lane];
        y1 += __shfl(f1, d, 64) * Wg[4096 + d * 64 + lane];
        y2 += __shfl(f2, d, 64) * Wg[8192 + d * 64 + lane];
      }
      float aux1 = f0 * y0, aux2 = f1 * y1, tgt = f2 * y2;
      float sc1 = wave_sum(tgt * ts[lane] + aux1 * ts[64 + lane]);
      float sc2 = wave_sum(tgt * ts[128 + lane] + aux2 * ts[192 + lane]);
      if (lane == 0) {
        storef(out, OFF_S1 + n, sc1, f32);
        storef(out, OFF_S2 + n, sc2, f32);
      }
    } else {
      int ob = OFF_I + (n - N_USERS) * RD + lane;
      storef(out, ob, f0, f32);
      storef(out, ob + 64, f1, f32);
      storef(out, ob + 128, f2, f32);
    }
  }
}

extern "C" void kernel_launch(void* const* d_in, const int* in_sizes, int n_in,
                              void* d_out, int out_size, void* d_ws,
                              size_t ws_size, hipStream_t stream) {
  const void* user_emb = d_in[0];
  const void* item_emb = d_in[1];
  const void* rel_emb = d_in[2];
  const void* W_gc = d_in[3];
  const void* W_rel = d_in[4];
  const void* gru_w = d_in[5];
  const void* gru_b = d_in[6];
  const void* tra = d_in[7];
  const void* adj_vals = d_in[8];
  const int* adj_rows = (const int*)d_in[9];
  const int* adj_cols = (const int*)d_in[10];

  // ws layout
  int* flag = (int*)d_ws;
  float* wsf = (float*)d_ws;
  float* rela_f = wsf + 16;                         // 576 floats
  float* all_emb = wsf + 1024;                      // 19.2M floats
  int* counts = (int*)(all_emb + (size_t)N_NODES * RD);   // 300k
  int* offs = counts + M3;
  int* cursors = offs + M3;
  int* bsums = cursors + M3;                        // 1024
  int* bsums2 = bsums + 1024;                       // 1024
  int* scol = bsums2 + 1024;                        // 4.8M
  bf16* sval = (bf16*)(scol + NE3);                 // 4.8M bf16
  bf16* ego_A = (bf16*)(sval + NE3);                // 19.2M bf16
  bf16* ego_B = ego_A + (size_t)N_NODES * RD;       // 19.2M bf16

  const int nbScan = (M3 + 1023) / 1024;            // 293

  detect_kernel<<<1, 256, 0, stream>>>((const unsigned short*)user_emb, flag);
  rela_kernel<<<1, 192, 0, stream>>>(rel_emb, W_rel, flag, rela_f, d_out);
  zero_row_kernel<<<1, 192, 0, stream>>>(d_out, flag);
  init_kernel<<<(N_NODES * RD + 255) / 256, 256, 0, stream>>>(
      user_emb, item_emb, flag, ego_A, all_emb);

  (void)hipMemsetAsync(counts, 0, (size_t)M3 * sizeof(int), stream);
  hist_kernel<<<(NE3 + 255) / 256, 256, 0, stream>>>(adj_rows, counts);
  scanA_kernel<<<nbScan, 1024, 0, stream>>>(counts, offs, bsums);
  scanB_kernel<<<1, 512, 0, stream>>>(bsums, bsums2, nbScan);
  scanC_kernel<<<nbScan, 1024, 0, stream>>>(offs, bsums2, cursors);
  reorder_kernel<<<(NE3 + 255) / 256, 256, 0, stream>>>(
      adj_rows, adj_cols, adj_vals, flag, cursors, scol, sval);

  gt_kernel<<<N_NODES / 32, 256, 0, stream>>>(
      scol, sval, counts, offs, rela_f, W_gc, 0, flag, ego_A, ego_B, all_emb);
  gt_kernel<<<N_NODES / 32, 256, 0, stream>>>(
      scol, sval, counts, offs, rela_f + 192, W_gc, 4096, flag, ego_B, ego_A,
      all_emb);

  final_kernel<<<(N_NODES + 63) / 64, 256, 0, stream>>>(
      all_emb, gru_w, gru_b, tra, flag, d_out);
}

// Round 5
// 2076.742 us; speedup vs baseline: 1.8122x; 1.8122x over previous
//
#include <hip/hip_runtime.h>
#include <hip/hip_bf16.h>

#define N_USERS 70000
#define N_ITEMS 30000
#define N_NODES 100000
#define RD 192      // R*D
#define EE 1600000
#define NE3 4800000
#define M3 300000   // 3 * N_NODES segments

// output element offsets (dtype-independent)
#define OFF_U    0
#define OFF_I    13440000
#define OFF_IZ   19200000   // zero row (item index 30000)
#define OFF_RELA 19200192
#define OFF_S1   19200384
#define OFF_S2   19270384

typedef __hip_bfloat16 bf16;

__device__ __forceinline__ float b2f(bf16 v) { return __bfloat162float(v); }

// dtype-adaptive IO: f32 -> fp32 arrays, else bf16 arrays
__device__ __forceinline__ float loadf(const void* p, int i, bool f32) {
  return f32 ? ((const float*)p)[i] : b2f(((const bf16*)p)[i]);
}
__device__ __forceinline__ void storef(void* p, int i, float v, bool f32) {
  if (f32) ((float*)p)[i] = v;
  else ((bf16*)p)[i] = __float2bfloat16(v);
}

__device__ __forceinline__ float wave_sum(float v) {
#pragma unroll
  for (int off = 32; off >= 1; off >>= 1) v += __shfl_xor(v, off, 64);
  return v;
}

__global__ void detect_kernel(const unsigned short* __restrict__ ue,
                              int* __restrict__ flag) {
  __shared__ int s;
  int t = threadIdx.x;
  if (t == 0) s = 0;
  __syncthreads();
  int big = 0;
  for (int j = t; j < 8192; j += 256) {
    int e = (ue[j] >> 7) & 0xFF;
    if (e >= 127) big = 1;
  }
  if (big) atomicOr(&s, 1);
  __syncthreads();
  if (t == 0) *flag = s;
}

__global__ void zero_row_kernel(void* out, const int* __restrict__ flag) {
  bool f32 = *flag != 0;
  storef(out, OFF_IZ + (int)threadIdx.x, 0.f, f32);  // 192 threads
}

// rela chain: rela0=rel_emb, rela1=rela0@W_rel[0], rela2=rela1@W_rel[1]
__global__ void rela_kernel(const void* __restrict__ rel_emb,
                            const void* __restrict__ W_rel,
                            const int* __restrict__ flag,
                            float* __restrict__ rela_f, void* out) {
  bool f32 = *flag != 0;
  __shared__ float r0s[192], r1s[192];
  int t = threadIdx.x;            // 192 threads
  int i = t >> 6, d = t & 63;
  float r0 = loadf(rel_emb, t, f32);
  r0s[t] = r0;
  __syncthreads();
  float acc = 0.f;
  for (int k = 0; k < 64; ++k)
    acc += r0s[i * 64 + k] * loadf(W_rel, k * 64 + d, f32);
  r1s[t] = acc;
  __syncthreads();
  float acc2 = 0.f;
  for (int k = 0; k < 64; ++k)
    acc2 += r1s[i * 64 + k] * loadf(W_rel, 4096 + k * 64 + d, f32);
  rela_f[t] = r0;
  rela_f[192 + t] = acc;
  rela_f[384 + t] = acc2;
  storef(out, OFF_RELA + t, (r0 + acc + acc2) * (1.f / 3.f), f32);
}

__global__ __launch_bounds__(256) void init_kernel(
    const void* __restrict__ user_emb, const void* __restrict__ item_emb,
    const int* __restrict__ flag, bf16* __restrict__ ego,
    float* __restrict__ all_emb) {
  bool f32 = *flag != 0;
  int idx = blockIdx.x * 256 + threadIdx.x;
  if (idx >= N_NODES * RD) return;
  int n = idx / RD;
  int rd = idx - n * RD;
  int d = rd & 63;
  float v = (n < N_USERS) ? loadf(user_emb, n * 64 + d, f32)
                          : loadf(item_emb, (n - N_USERS) * 64 + d, f32);
  ego[idx] = __float2bfloat16(v);
  all_emb[idx] = v;
}

// ---- CSR build ----
__global__ __launch_bounds__(256) void hist_kernel(
    const int* __restrict__ rows, int* __restrict__ counts) {
  int idx = blockIdx.x * 256 + threadIdx.x;
  if (idx >= NE3) return;
  int i = idx / EE;
  atomicAdd(counts + i * N_NODES + rows[idx], 1);
}

// block-level exclusive scan (1024/block), writes block totals
__global__ __launch_bounds__(1024) void scanA_kernel(
    const int* __restrict__ counts, int* __restrict__ offs,
    int* __restrict__ bsums) {
  __shared__ int s[1024];
  int t = threadIdx.x;
  int idx = blockIdx.x * 1024 + t;
  int x = (idx < M3) ? counts[idx] : 0;
  s[t] = x;
  __syncthreads();
  for (int off = 1; off < 1024; off <<= 1) {
    int y = (t >= off) ? s[t - off] : 0;
    __syncthreads();
    s[t] += y;
    __syncthreads();
  }
  if (idx < M3) offs[idx] = s[t] - x;
  if (t == 1023) bsums[blockIdx.x] = s[t];
}

__global__ __launch_bounds__(512) void scanB_kernel(
    const int* __restrict__ bsums, int* __restrict__ bsums2, int nb) {
  __shared__ int s[512];
  int t = threadIdx.x;
  int x = (t < nb) ? bsums[t] : 0;
  s[t] = x;
  __syncthreads();
  for (int off = 1; off < 512; off <<= 1) {
    int y = (t >= off) ? s[t - off] : 0;
    __syncthreads();
    s[t] += y;
    __syncthreads();
  }
  if (t < nb) bsums2[t] = s[t] - x;
}

__global__ __launch_bounds__(1024) void scanC_kernel(
    int* __restrict__ offs, const int* __restrict__ bsums2,
    int* __restrict__ cursors) {
  int idx = blockIdx.x * 1024 + threadIdx.x;
  if (idx >= M3) return;
  int v = offs[idx] + bsums2[blockIdx.x];
  offs[idx] = v;
  cursors[idx] = v;
}

// pack edges row-sorted as int2{col, fp32 val bits}
__global__ __launch_bounds__(256) void reorder_kernel(
    const int* __restrict__ rows, const int* __restrict__ cols,
    const void* __restrict__ vals, const int* __restrict__ flag,
    int* __restrict__ cursors, int2* __restrict__ sedge) {
  bool f32 = *flag != 0;
  int idx = blockIdx.x * 256 + threadIdx.x;
  if (idx >= NE3) return;
  int i = idx / EE;
  int r = rows[idx];
  float v = loadf(vals, idx, f32);
  int pos = atomicAdd(cursors + i * N_NODES + r, 1);
  int2 e;
  e.x = cols[idx];
  e.y = __float_as_int(v);
  sedge[pos] = e;
}

// one wave per (node, relation) segment; lane = dim. No atomics.
__global__ __launch_bounds__(256) void gather_kernel(
    const int2* __restrict__ sedge, const int* __restrict__ counts,
    const int* __restrict__ offs, const bf16* __restrict__ ego,
    bf16* __restrict__ prop) {
  int seg = blockIdx.x * 4 + (threadIdx.x >> 6);   // i*N_NODES + n
  int lane = threadIdx.x & 63;
  int i = seg / N_NODES;
  int n = seg - i * N_NODES;
  int base = offs[seg];
  int cnt = counts[seg];
  int i64 = i * 64;
  float acc = 0.f;
  int j = 0;
  for (; j + 8 <= cnt; j += 8) {
    int2 e[8];
#pragma unroll
    for (int u = 0; u < 8; ++u) e[u] = sedge[base + j + u];
    float g[8];
#pragma unroll
    for (int u = 0; u < 8; ++u) g[u] = b2f(ego[e[u].x * RD + i64 + lane]);
#pragma unroll
    for (int u = 0; u < 8; ++u) acc = fmaf(g[u], __int_as_float(e[u].y), acc);
  }
  for (; j < cnt; ++j) {
    int2 e = sedge[base + j];
    acc = fmaf(b2f(ego[e.x * RD + i64 + lane]), __int_as_float(e.y), acc);
  }
  prop[n * RD + i64 + lane] = __float2bfloat16(acc);
}

__device__ __forceinline__ float attn_row(float a, float b, float c,
                                          float e0, float e1, float e2) {
  float m = fmaxf(a, fmaxf(b, c));
  float w0 = __expf(a - m), w1 = __expf(b - m), w2 = __expf(c - m);
  float inv = 1.f / (w0 + w1 + w2);
  return (w0 * e0 + w1 * e1 + w2 * e2) * inv;
}

// 32 nodes per block. est = leaky_relu((prop*rela)@Wgc); per-node 3x3 attn;
// writes ego in place (safe: gather completed) and all_emb += ego.
__global__ __launch_bounds__(256) void transform_attn_kernel(
    const bf16* __restrict__ prop, const float* __restrict__ rela_k,
    const void* __restrict__ Wgc, int wgc_off, const int* __restrict__ flag,
    bf16* __restrict__ ego, float* __restrict__ all_emb) {
  bool f32 = *flag != 0;
  __shared__ float Ws[4096];
  __shared__ float est_s[32 * RD];
  int t = threadIdx.x, lane = t & 63, wave = t >> 6;
  for (int j = t; j < 4096; j += 256) Ws[j] = loadf(Wgc, wgc_off + j, f32);
  float rel0 = rela_k[lane], rel1 = rela_k[64 + lane], rel2 = rela_k[128 + lane];
  __syncthreads();
  int n0 = blockIdx.x * 32;
#pragma unroll
  for (int i = 0; i < 3; ++i) {
    float rel = (i == 0) ? rel0 : ((i == 1) ? rel1 : rel2);
    for (int nl = wave; nl < 32; nl += 4) {
      int n = n0 + nl;
      float x = b2f(prop[n * RD + i * 64 + lane]) * rel;
      float acc = 0.f;
#pragma unroll
      for (int d = 0; d < 64; ++d)
        acc += __shfl(x, d, 64) * Ws[d * 64 + lane];
      acc = acc > 0.f ? acc : 0.01f * acc;
      est_s[nl * RD + i * 64 + lane] = acc;
    }
  }
  __syncthreads();
  const float sc = 0.088388347648318447f;  // 1/sqrt(128)
  for (int jj = 0; jj < 8; ++jj) {
    int nl = wave * 8 + jj;
    int n = n0 + nl;
    float e0 = est_s[nl * RD + lane];
    float e1 = est_s[nl * RD + 64 + lane];
    float e2 = est_s[nl * RD + 128 + lane];
    float s00 = wave_sum(e0 * e0);
    float s01 = wave_sum(e0 * e1);
    float s02 = wave_sum(e0 * e2);
    float s11 = wave_sum(e1 * e1);
    float s12 = wave_sum(e1 * e2);
    float s22 = wave_sum(e2 * e2);
    float o0 = attn_row(s00 * sc, s01 * sc, s02 * sc, e0, e1, e2);
    float o1 = attn_row(s01 * sc, s11 * sc, s12 * sc, e0, e1, e2);
    float o2 = attn_row(s02 * sc, s12 * sc, s22 * sc, e0, e1, e2);
    int base = n * RD + lane;
    ego[base] = __float2bfloat16(o0);
    ego[base + 64] = __float2bfloat16(o1);
    ego[base + 128] = __float2bfloat16(o2);
    all_emb[base] += o0;
    all_emb[base + 64] += o1;
    all_emb[base + 128] += o2;
  }
}

// final attention (row 2 only) + outputs; users also do GRU matvecs + scores
__global__ __launch_bounds__(256) void final_kernel(
    const float* __restrict__ all_emb, const void* __restrict__ gru_w,
    const void* __restrict__ gru_b, const void* __restrict__ tra,
    const int* __restrict__ flag, void* out) {
  bool f32 = *flag != 0;
  __shared__ float Wg[3 * 4096];
  __shared__ float bs[192];
  __shared__ float ts[256];
  int t = threadIdx.x, lane = t & 63, wave = t >> 6;
  for (int j = t; j < 12288; j += 256) Wg[j] = loadf(gru_w, j, f32);
  if (t < 192) bs[t] = loadf(gru_b, t, f32);
  ts[t] = loadf(tra, t, f32);
  __syncthreads();
  int n0 = blockIdx.x * 64 + wave * 16;
  for (int jj = 0; jj < 16; ++jj) {
    int n = n0 + jj;
    if (n >= N_NODES) break;
    float a0 = all_emb[n * RD + lane];
    float a1 = all_emb[n * RD + 64 + lane];
    float a2 = all_emb[n * RD + 128 + lane];
    float s20 = wave_sum(a2 * a0);
    float s21 = wave_sum(a2 * a1);
    float s22 = wave_sum(a2 * a2);
    float mid2 = attn_row(s20, s21, s22, a0, a1, a2);
    float f0 = a0 * (1.f / 3.f), f1 = a1 * (1.f / 3.f), f2 = mid2 * (1.f / 3.f);
    if (n < N_USERS) {
      int ob = OFF_U + n * RD + lane;
      storef(out, ob, f0, f32);
      storef(out, ob + 64, f1, f32);
      storef(out, ob + 128, f2, f32);
      float y0 = bs[lane], y1 = bs[64 + lane], y2 = bs[128 + lane];
#pragma unroll
      for (int d = 0; d < 64; ++d) {
        y0 += __shfl(f0, d, 64) * Wg[d * 64 + lane];
        y1 += __shfl(f1, d, 64) * Wg[4096 + d * 64 + lane];
        y2 += __shfl(f2, d, 64) * Wg[8192 + d * 64 + lane];
      }
      float aux1 = f0 * y0, aux2 = f1 * y1, tgt = f2 * y2;
      float sc1 = wave_sum(tgt * ts[lane] + aux1 * ts[64 + lane]);
      float sc2 = wave_sum(tgt * ts[128 + lane] + aux2 * ts[192 + lane]);
      if (lane == 0) {
        storef(out, OFF_S1 + n, sc1, f32);
        storef(out, OFF_S2 + n, sc2, f32);
      }
    } else {
      int ob = OFF_I + (n - N_USERS) * RD + lane;
      storef(out, ob, f0, f32);
      storef(out, ob + 64, f1, f32);
      storef(out, ob + 128, f2, f32);
    }
  }
}

extern "C" void kernel_launch(void* const* d_in, const int* in_sizes, int n_in,
                              void* d_out, int out_size, void* d_ws,
                              size_t ws_size, hipStream_t stream) {
  const void* user_emb = d_in[0];
  const void* item_emb = d_in[1];
  const void* rel_emb = d_in[2];
  const void* W_gc = d_in[3];
  const void* W_rel = d_in[4];
  const void* gru_w = d_in[5];
  const void* gru_b = d_in[6];
  const void* tra = d_in[7];
  const void* adj_vals = d_in[8];
  const int* adj_rows = (const int*)d_in[9];
  const int* adj_cols = (const int*)d_in[10];

  // ws layout (~196 MB)
  int* flag = (int*)d_ws;
  float* wsf = (float*)d_ws;
  float* rela_f = wsf + 16;                          // 576 floats
  float* all_emb = wsf + 1024;                       // 19.2M floats
  int* counts = (int*)(all_emb + (size_t)N_NODES * RD);  // 300k
  int* offs = counts + M3;
  int* cursors = offs + M3;
  int* bsums = cursors + M3;                         // 1024
  int* bsums2 = bsums + 1024;                        // 1024
  int2* sedge = (int2*)(bsums2 + 1024);              // 4.8M int2 (aligned: offset even)
  bf16* ego = (bf16*)(sedge + NE3);                  // 19.2M bf16
  bf16* prop = ego + (size_t)N_NODES * RD;           // 19.2M bf16

  const int nbScan = (M3 + 1023) / 1024;             // 293

  detect_kernel<<<1, 256, 0, stream>>>((const unsigned short*)user_emb, flag);
  rela_kernel<<<1, 192, 0, stream>>>(rel_emb, W_rel, flag, rela_f, d_out);
  zero_row_kernel<<<1, 192, 0, stream>>>(d_out, flag);
  init_kernel<<<(N_NODES * RD + 255) / 256, 256, 0, stream>>>(
      user_emb, item_emb, flag, ego, all_emb);

  (void)hipMemsetAsync(counts, 0, (size_t)M3 * sizeof(int), stream);
  hist_kernel<<<(NE3 + 255) / 256, 256, 0, stream>>>(adj_rows, counts);
  scanA_kernel<<<nbScan, 1024, 0, stream>>>(counts, offs, bsums);
  scanB_kernel<<<1, 512, 0, stream>>>(bsums, bsums2, nbScan);
  scanC_kernel<<<nbScan, 1024, 0, stream>>>(offs, bsums2, cursors);
  reorder_kernel<<<(NE3 + 255) / 256, 256, 0, stream>>>(
      adj_rows, adj_cols, adj_vals, flag, cursors, sedge);

  for (int k = 0; k < 2; ++k) {
    gather_kernel<<<M3 / 4, 256, 0, stream>>>(sedge, counts, offs, ego, prop);
    transform_attn_kernel<<<N_NODES / 32, 256, 0, stream>>>(
        prop, rela_f + k * 192, W_gc, k * 4096, flag, ego, all_emb);
  }

  final_kernel<<<(N_NODES + 63) / 64, 256, 0, stream>>>(
      all_emb, gru_w, gru_b, tra, flag, d_out);
}

// Round 6
// 1797.541 us; speedup vs baseline: 2.0937x; 1.1553x over previous
//
#include <hip/hip_runtime.h>
#include <hip/hip_bf16.h>

#define N_USERS 70000
#define N_ITEMS 30000
#define N_NODES 100000
#define RD 192      // R*D
#define EE 1600000
#define NE3 4800000
#define M3 300000   // 3 * N_NODES segments
#define NSUB 98     // ceil(100000/1024) row sub-buckets
#define NBUCK 294   // 3 * NSUB

// output element offsets (dtype-independent)
#define OFF_U    0
#define OFF_I    13440000
#define OFF_IZ   19200000   // zero row (item index 30000)
#define OFF_RELA 19200192
#define OFF_S1   19200384
#define OFF_S2   19270384

typedef __hip_bfloat16 bf16;
typedef unsigned long long u64;

__device__ __forceinline__ float b2f(bf16 v) { return __bfloat162float(v); }

union bfbits { bf16 b; unsigned short u; };

__device__ __forceinline__ float bits2f(unsigned short u) {
  bfbits x; x.u = u; return b2f(x.b);
}
__device__ __forceinline__ unsigned short f2bits(float f) {
  bfbits x; x.b = __float2bfloat16(f); return x.u;
}

// dtype-adaptive IO: f32 -> fp32 arrays, else bf16 arrays
__device__ __forceinline__ float loadf(const void* p, int i, bool f32) {
  return f32 ? ((const float*)p)[i] : b2f(((const bf16*)p)[i]);
}
__device__ __forceinline__ void storef(void* p, int i, float v, bool f32) {
  if (f32) ((float*)p)[i] = v;
  else ((bf16*)p)[i] = __float2bfloat16(v);
}

__device__ __forceinline__ float wave_sum(float v) {
#pragma unroll
  for (int off = 32; off >= 1; off >>= 1) v += __shfl_xor(v, off, 64);
  return v;
}

__global__ void detect_kernel(const unsigned short* __restrict__ ue,
                              int* __restrict__ flag) {
  __shared__ int s;
  int t = threadIdx.x;
  if (t == 0) s = 0;
  __syncthreads();
  int big = 0;
  for (int j = t; j < 8192; j += 256) {
    int e = (ue[j] >> 7) & 0xFF;
    if (e >= 127) big = 1;
  }
  if (big) atomicOr(&s, 1);
  __syncthreads();
  if (t == 0) *flag = s;
}

__global__ void zero_row_kernel(void* out, const int* __restrict__ flag) {
  bool f32 = *flag != 0;
  storef(out, OFF_IZ + (int)threadIdx.x, 0.f, f32);  // 192 threads
}

// rela chain: rela0=rel_emb, rela1=rela0@W_rel[0], rela2=rela1@W_rel[1]
__global__ void rela_kernel(const void* __restrict__ rel_emb,
                            const void* __restrict__ W_rel,
                            const int* __restrict__ flag,
                            float* __restrict__ rela_f, void* out) {
  bool f32 = *flag != 0;
  __shared__ float r0s[192], r1s[192];
  int t = threadIdx.x;            // 192 threads
  int i = t >> 6, d = t & 63;
  float r0 = loadf(rel_emb, t, f32);
  r0s[t] = r0;
  __syncthreads();
  float acc = 0.f;
  for (int k = 0; k < 64; ++k)
    acc += r0s[i * 64 + k] * loadf(W_rel, k * 64 + d, f32);
  r1s[t] = acc;
  __syncthreads();
  float acc2 = 0.f;
  for (int k = 0; k < 64; ++k)
    acc2 += r1s[i * 64 + k] * loadf(W_rel, 4096 + k * 64 + d, f32);
  rela_f[t] = r0;
  rela_f[192 + t] = acc;
  rela_f[384 + t] = acc2;
  storef(out, OFF_RELA + t, (r0 + acc + acc2) * (1.f / 3.f), f32);
}

__global__ __launch_bounds__(256) void init_kernel(
    const void* __restrict__ user_emb, const void* __restrict__ item_emb,
    const int* __restrict__ flag, bf16* __restrict__ ego0) {
  bool f32 = *flag != 0;
  int idx = blockIdx.x * 256 + threadIdx.x;
  if (idx >= N_NODES * RD) return;
  int n = idx / RD;
  int rd = idx - n * RD;
  int d = rd & 63;
  float v = (n < N_USERS) ? loadf(user_emb, n * 64 + d, f32)
                          : loadf(item_emb, (n - N_USERS) * 64 + d, f32);
  ego0[idx] = __float2bfloat16(v);
}

// ---- CSR build ----
__global__ __launch_bounds__(256) void hist_kernel(
    const int* __restrict__ rows, int* __restrict__ counts) {
  int idx = blockIdx.x * 256 + threadIdx.x;
  if (idx >= NE3) return;
  int i = idx / EE;
  atomicAdd(counts + i * N_NODES + rows[idx], 1);
}

// block-level exclusive scan (1024/block), writes block totals
__global__ __launch_bounds__(1024) void scanA_kernel(
    const int* __restrict__ counts, int* __restrict__ offs,
    int* __restrict__ bsums) {
  __shared__ int s[1024];
  int t = threadIdx.x;
  int idx = blockIdx.x * 1024 + t;
  int x = (idx < M3) ? counts[idx] : 0;
  s[t] = x;
  __syncthreads();
  for (int off = 1; off < 1024; off <<= 1) {
    int y = (t >= off) ? s[t - off] : 0;
    __syncthreads();
    s[t] += y;
    __syncthreads();
  }
  if (idx < M3) offs[idx] = s[t] - x;
  if (t == 1023) bsums[blockIdx.x] = s[t];
}

__global__ __launch_bounds__(512) void scanB_kernel(
    const int* __restrict__ bsums, int* __restrict__ bsums2, int nb) {
  __shared__ int s[512];
  int t = threadIdx.x;
  int x = (t < nb) ? bsums[t] : 0;
  s[t] = x;
  __syncthreads();
  for (int off = 1; off < 512; off <<= 1) {
    int y = (t >= off) ? s[t - off] : 0;
    __syncthreads();
    s[t] += y;
    __syncthreads();
  }
  if (t < nb) bsums2[t] = s[t] - x;
}

__global__ __launch_bounds__(1024) void scanC_kernel(
    int* __restrict__ offs, const int* __restrict__ bsums2) {
  int idx = blockIdx.x * 1024 + threadIdx.x;
  if (idx >= M3) return;
  offs[idx] += bsums2[blockIdx.x];
}

// bucket base cursors: gcursor[b] = offs[first row of bucket]
__global__ void binit_kernel(const int* __restrict__ offs,
                             int* __restrict__ gcursor) {
  int b = threadIdx.x;   // 512 threads
  if (b >= NBUCK) return;
  int rel = b / NSUB, sub = b - rel * NSUB;
  gcursor[b] = offs[rel * N_NODES + (sub << 10)];
}

// Pass A: bucket edges into 294 (rel, row>>10) buckets; runs are
// block-contiguous -> L2 coalesces lines. Packed u64: rowlo<<48|col<<16|bf16
__global__ __launch_bounds__(256) void passA_kernel(
    const int* __restrict__ rows, const int* __restrict__ cols,
    const void* __restrict__ vals, const int* __restrict__ flag,
    int* __restrict__ gcursor, u64* __restrict__ abuf) {
  bool f32 = *flag != 0;
  __shared__ u64 pk[4096];
  __shared__ unsigned short bk[4096];
  __shared__ int cnt[NBUCK], pos[NBUCK], gbase[NBUCK];
  int t = threadIdx.x;
  for (int j = t; j < NBUCK; j += 256) { cnt[j] = 0; pos[j] = 0; }
  __syncthreads();
  int base = blockIdx.x * 4096;
  int m = min(4096, NE3 - base);
  for (int j = t; j < m; j += 256) {
    int idx = base + j;
    int i = idx / EE;
    int r = rows[idx];
    int c = cols[idx];
    unsigned short vb =
        f32 ? f2bits(((const float*)vals)[idx])
            : ((const unsigned short*)vals)[idx];
    int sub = r >> 10;
    int b = i * NSUB + sub;
    pk[j] = ((u64)(r & 1023) << 48) | ((u64)(unsigned)c << 16) | vb;
    bk[j] = (unsigned short)b;
    atomicAdd(&cnt[b], 1);
  }
  __syncthreads();
  for (int j = t; j < NBUCK; j += 256)
    if (cnt[j] > 0) gbase[j] = atomicAdd(&gcursor[j], cnt[j]);
  __syncthreads();
  for (int j = t; j < m; j += 256) {
    int b = bk[j];
    int p = atomicAdd(&pos[b], 1);
    abuf[gbase[b] + p] = pk[j];
  }
}

// Pass B: one block per bucket; LDS row cursors; dest range ~130KB contiguous
__global__ __launch_bounds__(256) void passB_kernel(
    const u64* __restrict__ abuf, const int* __restrict__ offs,
    int2* __restrict__ sedge) {
  __shared__ int curs[1024];
  int b = blockIdx.x;
  int rel = b / NSUB, sub = b - rel * NSUB;
  int r0 = sub << 10;
  int nr = min(1024, N_NODES - r0);
  int gi = rel * N_NODES + r0;
  int t = threadIdx.x;
  for (int j = t; j < nr; j += 256) curs[j] = offs[gi + j];
  __syncthreads();
  int base = offs[gi];
  int endi = gi + nr;
  int end = (endi < M3) ? offs[endi] : NE3;
  for (int e = base + t; e < end; e += 256) {
    u64 w = abuf[e];
    int rowlo = (int)(w >> 48);
    int c = (int)((w >> 16) & 0x3FFFF);
    float v = bits2f((unsigned short)(w & 0xFFFF));
    int p = atomicAdd(&curs[rowlo], 1);
    int2 eo; eo.x = c; eo.y = __float_as_int(v);
    sedge[p] = eo;
  }
}

// one wave per (node, relation) segment; lane = dim. No atomics.
__global__ __launch_bounds__(256) void gather_kernel(
    const int2* __restrict__ sedge, const int* __restrict__ counts,
    const int* __restrict__ offs, const bf16* __restrict__ ego,
    bf16* __restrict__ prop) {
  int seg = blockIdx.x * 4 + (threadIdx.x >> 6);   // i*N_NODES + n
  int lane = threadIdx.x & 63;
  int i = seg / N_NODES;
  int n = seg - i * N_NODES;
  int base = offs[seg];
  int cnt = counts[seg];
  int i64 = i * 64;
  float acc = 0.f;
  int j = 0;
  for (; j + 8 <= cnt; j += 8) {
    int2 e[8];
#pragma unroll
    for (int u = 0; u < 8; ++u) e[u] = sedge[base + j + u];
    float g[8];
#pragma unroll
    for (int u = 0; u < 8; ++u) g[u] = b2f(ego[e[u].x * RD + i64 + lane]);
#pragma unroll
    for (int u = 0; u < 8; ++u) acc = fmaf(g[u], __int_as_float(e[u].y), acc);
  }
  for (; j < cnt; ++j) {
    int2 e = sedge[base + j];
    acc = fmaf(b2f(ego[e.x * RD + i64 + lane]), __int_as_float(e.y), acc);
  }
  prop[n * RD + i64 + lane] = __float2bfloat16(acc);
}

__device__ __forceinline__ float attn_row(float a, float b, float c,
                                          float e0, float e1, float e2) {
  float m = fmaxf(a, fmaxf(b, c));
  float w0 = __expf(a - m), w1 = __expf(b - m), w2 = __expf(c - m);
  float inv = 1.f / (w0 + w1 + w2);
  return (w0 * e0 + w1 * e1 + w2 * e2) * inv;
}

// 32 nodes per block. est = leaky_relu((prop*rela)@Wgc); per-node 3x3 attn;
// writes ego_out (bf16). No all_emb accumulator (summed in final).
__global__ __launch_bounds__(256) void transform_attn_kernel(
    const bf16* __restrict__ prop, const float* __restrict__ rela_k,
    const void* __restrict__ Wgc, int wgc_off, const int* __restrict__ flag,
    bf16* __restrict__ ego_out) {
  bool f32 = *flag != 0;
  __shared__ float Ws[4096];
  __shared__ float est_s[32 * RD];
  int t = threadIdx.x, lane = t & 63, wave = t >> 6;
  for (int j = t; j < 4096; j += 256) Ws[j] = loadf(Wgc, wgc_off + j, f32);
  float rel0 = rela_k[lane], rel1 = rela_k[64 + lane], rel2 = rela_k[128 + lane];
  __syncthreads();
  int n0 = blockIdx.x * 32;
#pragma unroll
  for (int i = 0; i < 3; ++i) {
    float rel = (i == 0) ? rel0 : ((i == 1) ? rel1 : rel2);
    for (int nl = wave; nl < 32; nl += 4) {
      int n = n0 + nl;
      float x = b2f(prop[n * RD + i * 64 + lane]) * rel;
      float acc = 0.f;
#pragma unroll
      for (int d = 0; d < 64; ++d)
        acc += __shfl(x, d, 64) * Ws[d * 64 + lane];
      acc = acc > 0.f ? acc : 0.01f * acc;
      est_s[nl * RD + i * 64 + lane] = acc;
    }
  }
  __syncthreads();
  const float sc = 0.088388347648318447f;  // 1/sqrt(128)
  for (int jj = 0; jj < 8; ++jj) {
    int nl = wave * 8 + jj;
    int n = n0 + nl;
    float e0 = est_s[nl * RD + lane];
    float e1 = est_s[nl * RD + 64 + lane];
    float e2 = est_s[nl * RD + 128 + lane];
    float s00 = wave_sum(e0 * e0);
    float s01 = wave_sum(e0 * e1);
    float s02 = wave_sum(e0 * e2);
    float s11 = wave_sum(e1 * e1);
    float s12 = wave_sum(e1 * e2);
    float s22 = wave_sum(e2 * e2);
    float o0 = attn_row(s00 * sc, s01 * sc, s02 * sc, e0, e1, e2);
    float o1 = attn_row(s01 * sc, s11 * sc, s12 * sc, e0, e1, e2);
    float o2 = attn_row(s02 * sc, s12 * sc, s22 * sc, e0, e1, e2);
    int base = n * RD + lane;
    ego_out[base] = __float2bfloat16(o0);
    ego_out[base + 64] = __float2bfloat16(o1);
    ego_out[base + 128] = __float2bfloat16(o2);
  }
}

// final attention (row 2 only) + outputs; users also do GRU matvecs + scores
__global__ __launch_bounds__(256) void final_kernel(
    const bf16* __restrict__ ego0, const bf16* __restrict__ ego1,
    const bf16* __restrict__ ego2, const void* __restrict__ gru_w,
    const void* __restrict__ gru_b, const void* __restrict__ tra,
    const int* __restrict__ flag, void* out) {
  bool f32 = *flag != 0;
  __shared__ float Wg[3 * 4096];
  __shared__ float bs[192];
  __shared__ float ts[256];
  int t = threadIdx.x, lane = t & 63, wave = t >> 6;
  for (int j = t; j < 12288; j += 256) Wg[j] = loadf(gru_w, j, f32);
  if (t < 192) bs[t] = loadf(gru_b, t, f32);
  ts[t] = loadf(tra, t, f32);
  __syncthreads();
  int n0 = blockIdx.x * 64 + wave * 16;
  for (int jj = 0; jj < 16; ++jj) {
    int n = n0 + jj;
    if (n >= N_NODES) break;
    int b0 = n * RD + lane;
    float a0 = b2f(ego0[b0]) + b2f(ego1[b0]) + b2f(ego2[b0]);
    float a1 = b2f(ego0[b0 + 64]) + b2f(ego1[b0 + 64]) + b2f(ego2[b0 + 64]);
    float a2 = b2f(ego0[b0 + 128]) + b2f(ego1[b0 + 128]) + b2f(ego2[b0 + 128]);
    float s20 = wave_sum(a2 * a0);
    float s21 = wave_sum(a2 * a1);
    float s22 = wave_sum(a2 * a2);
    float mid2 = attn_row(s20, s21, s22, a0, a1, a2);
    float f0 = a0 * (1.f / 3.f), f1 = a1 * (1.f / 3.f), f2 = mid2 * (1.f / 3.f);
    if (n < N_USERS) {
      int ob = OFF_U + n * RD + lane;
      storef(out, ob, f0, f32);
      storef(out, ob + 64, f1, f32);
      storef(out, ob + 128, f2, f32);
      float y0 = bs[lane], y1 = bs[64 + lane], y2 = bs[128 + lane];
#pragma unroll
      for (int d = 0; d < 64; ++d) {
        y0 += __shfl(f0, d, 64) * Wg[d * 64 + lane];
        y1 += __shfl(f1, d, 64) * Wg[4096 + d * 64 + lane];
        y2 += __shfl(f2, d, 64) * Wg[8192 + d * 64 + lane];
      }
      float aux1 = f0 * y0, aux2 = f1 * y1, tgt = f2 * y2;
      float sc1 = wave_sum(tgt * ts[lane] + aux1 * ts[64 + lane]);
      float sc2 = wave_sum(tgt * ts[128 + lane] + aux2 * ts[192 + lane]);
      if (lane == 0) {
        storef(out, OFF_S1 + n, sc1, f32);
        storef(out, OFF_S2 + n, sc2, f32);
      }
    } else {
      int ob = OFF_I + (n - N_USERS) * RD + lane;
      storef(out, ob, f0, f32);
      storef(out, ob + 64, f1, f32);
      storef(out, ob + 128, f2, f32);
    }
  }
}

extern "C" void kernel_launch(void* const* d_in, const int* in_sizes, int n_in,
                              void* d_out, int out_size, void* d_ws,
                              size_t ws_size, hipStream_t stream) {
  const void* user_emb = d_in[0];
  const void* item_emb = d_in[1];
  const void* rel_emb = d_in[2];
  const void* W_gc = d_in[3];
  const void* W_rel = d_in[4];
  const void* gru_w = d_in[5];
  const void* gru_b = d_in[6];
  const void* tra = d_in[7];
  const void* adj_vals = d_in[8];
  const int* adj_rows = (const int*)d_in[9];
  const int* adj_cols = (const int*)d_in[10];

  // ws layout (~156 MB)
  int* flag = (int*)d_ws;
  float* wsf = (float*)d_ws;
  float* rela_f = wsf + 16;                       // 576 floats
  int* counts = (int*)(wsf + 1024);               // 300k
  int* offs = counts + M3;                        // 300k
  int* gcursor = offs + M3;                       // 512
  int* bsums = gcursor + 512;                     // 1024
  int* bsums2 = bsums + 1024;                     // 1024
  u64* abuf = (u64*)(bsums2 + 1024);              // 4.8M u64 (8B-aligned)
  int2* sedge = (int2*)(abuf + NE3);              // 4.8M int2
  bf16* ego0 = (bf16*)(sedge + NE3);              // 19.2M bf16
  bf16* ego1 = ego0 + (size_t)N_NODES * RD;
  bf16* ego2 = ego1 + (size_t)N_NODES * RD;
  bf16* prop = ego2 + (size_t)N_NODES * RD;

  const int nbScan = (M3 + 1023) / 1024;          // 293

  detect_kernel<<<1, 256, 0, stream>>>((const unsigned short*)user_emb, flag);
  rela_kernel<<<1, 192, 0, stream>>>(rel_emb, W_rel, flag, rela_f, d_out);
  zero_row_kernel<<<1, 192, 0, stream>>>(d_out, flag);
  init_kernel<<<(N_NODES * RD + 255) / 256, 256, 0, stream>>>(
      user_emb, item_emb, flag, ego0);

  (void)hipMemsetAsync(counts, 0, (size_t)M3 * sizeof(int), stream);
  hist_kernel<<<(NE3 + 255) / 256, 256, 0, stream>>>(adj_rows, counts);
  scanA_kernel<<<nbScan, 1024, 0, stream>>>(counts, offs, bsums);
  scanB_kernel<<<1, 512, 0, stream>>>(bsums, bsums2, nbScan);
  scanC_kernel<<<nbScan, 1024, 0, stream>>>(offs, bsums2);
  binit_kernel<<<1, 512, 0, stream>>>(offs, gcursor);
  passA_kernel<<<(NE3 + 4095) / 4096, 256, 0, stream>>>(
      adj_rows, adj_cols, adj_vals, flag, gcursor, abuf);
  passB_kernel<<<NBUCK, 256, 0, stream>>>(abuf, offs, sedge);

  gather_kernel<<<M3 / 4, 256, 0, stream>>>(sedge, counts, offs, ego0, prop);
  transform_attn_kernel<<<N_NODES / 32, 256, 0, stream>>>(
      prop, rela_f, W_gc, 0, flag, ego1);
  gather_kernel<<<M3 / 4, 256, 0, stream>>>(sedge, counts, offs, ego1, prop);
  transform_attn_kernel<<<N_NODES / 32, 256, 0, stream>>>(
      prop, rela_f + 192, W_gc, 4096, flag, ego2);

  final_kernel<<<(N_NODES + 63) / 64, 256, 0, stream>>>(
      ego0, ego1, ego2, gru_w, gru_b, tra, flag, d_out);
}

// Round 7
// 1308.763 us; speedup vs baseline: 2.8756x; 1.3735x over previous
//
#include <hip/hip_runtime.h>
#include <hip/hip_bf16.h>

#define N_USERS 70000
#define N_ITEMS 30000
#define N_NODES 100000
#define RD 192      // R*D
#define EE 1600000
#define NE3 4800000
#define M3 300000   // 3 * N_NODES segments
#define NSUB 98     // ceil(100000/1024) row sub-buckets
#define NBUCK 294   // 3 * NSUB

// output element offsets (dtype-independent)
#define OFF_U    0
#define OFF_I    13440000
#define OFF_IZ   19200000   // zero row (item index 30000)
#define OFF_RELA 19200192
#define OFF_S1   19200384
#define OFF_S2   19270384

typedef __hip_bfloat16 bf16;
typedef unsigned long long u64;
typedef __attribute__((ext_vector_type(8))) short short8;
typedef __attribute__((ext_vector_type(8))) unsigned short ushort8;
typedef __attribute__((ext_vector_type(4))) float f32x4;

__device__ __forceinline__ float b2f(bf16 v) { return __bfloat162float(v); }

union bfbits { bf16 b; unsigned short u; };

__device__ __forceinline__ float bits2f(unsigned short u) {
  bfbits x; x.u = u; return b2f(x.b);
}
__device__ __forceinline__ unsigned short f2bits(float f) {
  bfbits x; x.b = __float2bfloat16(f); return x.u;
}

// dtype-adaptive IO: f32 -> fp32 arrays, else bf16 arrays
__device__ __forceinline__ float loadf(const void* p, int i, bool f32) {
  return f32 ? ((const float*)p)[i] : b2f(((const bf16*)p)[i]);
}
__device__ __forceinline__ void storef(void* p, int i, float v, bool f32) {
  if (f32) ((float*)p)[i] = v;
  else ((bf16*)p)[i] = __float2bfloat16(v);
}

__device__ __forceinline__ float wave_sum(float v) {
#pragma unroll
  for (int off = 32; off >= 1; off >>= 1) v += __shfl_xor(v, off, 64);
  return v;
}

__global__ void detect_kernel(const unsigned short* __restrict__ ue,
                              int* __restrict__ flag) {
  __shared__ int s;
  int t = threadIdx.x;
  if (t == 0) s = 0;
  __syncthreads();
  int big = 0;
  for (int j = t; j < 8192; j += 256) {
    int e = (ue[j] >> 7) & 0xFF;
    if (e >= 127) big = 1;
  }
  if (big) atomicOr(&s, 1);
  __syncthreads();
  if (t == 0) *flag = s;
}

__global__ void zero_row_kernel(void* out, const int* __restrict__ flag) {
  bool f32 = *flag != 0;
  storef(out, OFF_IZ + (int)threadIdx.x, 0.f, f32);  // 192 threads
}

// rela chain: rela0=rel_emb, rela1=rela0@W_rel[0], rela2=rela1@W_rel[1]
__global__ void rela_kernel(const void* __restrict__ rel_emb,
                            const void* __restrict__ W_rel,
                            const int* __restrict__ flag,
                            float* __restrict__ rela_f, void* out) {
  bool f32 = *flag != 0;
  __shared__ float r0s[192], r1s[192];
  int t = threadIdx.x;            // 192 threads
  int i = t >> 6, d = t & 63;
  float r0 = loadf(rel_emb, t, f32);
  r0s[t] = r0;
  __syncthreads();
  float acc = 0.f;
  for (int k = 0; k < 64; ++k)
    acc += r0s[i * 64 + k] * loadf(W_rel, k * 64 + d, f32);
  r1s[t] = acc;
  __syncthreads();
  float acc2 = 0.f;
  for (int k = 0; k < 64; ++k)
    acc2 += r1s[i * 64 + k] * loadf(W_rel, 4096 + k * 64 + d, f32);
  rela_f[t] = r0;
  rela_f[192 + t] = acc;
  rela_f[384 + t] = acc2;
  storef(out, OFF_RELA + t, (r0 + acc + acc2) * (1.f / 3.f), f32);
}

__global__ __launch_bounds__(256) void init_kernel(
    const void* __restrict__ user_emb, const void* __restrict__ item_emb,
    const int* __restrict__ flag, bf16* __restrict__ ego0) {
  bool f32 = *flag != 0;
  int idx = blockIdx.x * 256 + threadIdx.x;
  if (idx >= N_NODES * RD) return;
  int n = idx / RD;
  int rd = idx - n * RD;
  int d = rd & 63;
  float v = (n < N_USERS) ? loadf(user_emb, n * 64 + d, f32)
                          : loadf(item_emb, (n - N_USERS) * 64 + d, f32);
  ego0[idx] = __float2bfloat16(v);
}

// ---- CSR build ----
__global__ __launch_bounds__(256) void hist_kernel(
    const int* __restrict__ rows, int* __restrict__ counts) {
  int idx = blockIdx.x * 256 + threadIdx.x;
  if (idx >= NE3) return;
  int i = idx / EE;
  atomicAdd(counts + i * N_NODES + rows[idx], 1);
}

// block-level exclusive scan (1024/block), writes block totals
__global__ __launch_bounds__(1024) void scanA_kernel(
    const int* __restrict__ counts, int* __restrict__ offs,
    int* __restrict__ bsums) {
  __shared__ int s[1024];
  int t = threadIdx.x;
  int idx = blockIdx.x * 1024 + t;
  int x = (idx < M3) ? counts[idx] : 0;
  s[t] = x;
  __syncthreads();
  for (int off = 1; off < 1024; off <<= 1) {
    int y = (t >= off) ? s[t - off] : 0;
    __syncthreads();
    s[t] += y;
    __syncthreads();
  }
  if (idx < M3) offs[idx] = s[t] - x;
  if (t == 1023) bsums[blockIdx.x] = s[t];
}

__global__ __launch_bounds__(512) void scanB_kernel(
    const int* __restrict__ bsums, int* __restrict__ bsums2, int nb) {
  __shared__ int s[512];
  int t = threadIdx.x;
  int x = (t < nb) ? bsums[t] : 0;
  s[t] = x;
  __syncthreads();
  for (int off = 1; off < 512; off <<= 1) {
    int y = (t >= off) ? s[t - off] : 0;
    __syncthreads();
    s[t] += y;
    __syncthreads();
  }
  if (t < nb) bsums2[t] = s[t] - x;
}

__global__ __launch_bounds__(1024) void scanC_kernel(
    int* __restrict__ offs, const int* __restrict__ bsums2) {
  int idx = blockIdx.x * 1024 + threadIdx.x;
  if (idx >= M3) return;
  offs[idx] += bsums2[blockIdx.x];
}

// bucket base cursors: gcursor[b] = offs[first row of bucket]
__global__ void binit_kernel(const int* __restrict__ offs,
                             int* __restrict__ gcursor) {
  int b = threadIdx.x;   // 512 threads
  if (b >= NBUCK) return;
  int rel = b / NSUB, sub = b - rel * NSUB;
  gcursor[b] = offs[rel * N_NODES + (sub << 10)];
}

// Pass A: bucket edges into 294 (rel, row>>10) buckets; runs are
// block-contiguous -> L2 coalesces lines. Packed u64: rowlo<<48|col<<16|bf16
__global__ __launch_bounds__(256) void passA_kernel(
    const int* __restrict__ rows, const int* __restrict__ cols,
    const void* __restrict__ vals, const int* __restrict__ flag,
    int* __restrict__ gcursor, u64* __restrict__ abuf) {
  bool f32 = *flag != 0;
  __shared__ u64 pk[4096];
  __shared__ unsigned short bk[4096];
  __shared__ int cnt[NBUCK], pos[NBUCK], gbase[NBUCK];
  int t = threadIdx.x;
  for (int j = t; j < NBUCK; j += 256) { cnt[j] = 0; pos[j] = 0; }
  __syncthreads();
  int base = blockIdx.x * 4096;
  int m = min(4096, NE3 - base);
  for (int j = t; j < m; j += 256) {
    int idx = base + j;
    int i = idx / EE;
    int r = rows[idx];
    int c = cols[idx];
    unsigned short vb =
        f32 ? f2bits(((const float*)vals)[idx])
            : ((const unsigned short*)vals)[idx];
    int sub = r >> 10;
    int b = i * NSUB + sub;
    pk[j] = ((u64)(r & 1023) << 48) | ((u64)(unsigned)c << 16) | vb;
    bk[j] = (unsigned short)b;
    atomicAdd(&cnt[b], 1);
  }
  __syncthreads();
  for (int j = t; j < NBUCK; j += 256)
    if (cnt[j] > 0) gbase[j] = atomicAdd(&gcursor[j], cnt[j]);
  __syncthreads();
  for (int j = t; j < m; j += 256) {
    int b = bk[j];
    int p = atomicAdd(&pos[b], 1);
    abuf[gbase[b] + p] = pk[j];
  }
}

// Pass B: one block per bucket; LDS row cursors; dest range ~130KB contiguous
__global__ __launch_bounds__(256) void passB_kernel(
    const u64* __restrict__ abuf, const int* __restrict__ offs,
    int2* __restrict__ sedge) {
  __shared__ int curs[1024];
  int b = blockIdx.x;
  int rel = b / NSUB, sub = b - rel * NSUB;
  int r0 = sub << 10;
  int nr = min(1024, N_NODES - r0);
  int gi = rel * N_NODES + r0;
  int t = threadIdx.x;
  for (int j = t; j < nr; j += 256) curs[j] = offs[gi + j];
  __syncthreads();
  int base = offs[gi];
  int endi = gi + nr;
  int end = (endi < M3) ? offs[endi] : NE3;
  for (int e = base + t; e < end; e += 256) {
    u64 w = abuf[e];
    int rowlo = (int)(w >> 48);
    int c = (int)((w >> 16) & 0x3FFFF);
    float v = bits2f((unsigned short)(w & 0xFFFF));
    int p = atomicAdd(&curs[rowlo], 1);
    int2 eo; eo.x = c; eo.y = __float_as_int(v);
    sedge[p] = eo;
  }
}

// one wave per (node, relation) segment; lane = dim. No atomics.
__global__ __launch_bounds__(256) void gather_kernel(
    const int2* __restrict__ sedge, const int* __restrict__ counts,
    const int* __restrict__ offs, const bf16* __restrict__ ego,
    bf16* __restrict__ prop) {
  int seg = blockIdx.x * 4 + (threadIdx.x >> 6);   // i*N_NODES + n
  int lane = threadIdx.x & 63;
  int i = seg / N_NODES;
  int n = seg - i * N_NODES;
  int base = offs[seg];
  int cnt = counts[seg];
  int i64 = i * 64;
  float acc = 0.f;
  int j = 0;
  for (; j + 8 <= cnt; j += 8) {
    int2 e[8];
#pragma unroll
    for (int u = 0; u < 8; ++u) e[u] = sedge[base + j + u];
    float g[8];
#pragma unroll
    for (int u = 0; u < 8; ++u) g[u] = b2f(ego[e[u].x * RD + i64 + lane]);
#pragma unroll
    for (int u = 0; u < 8; ++u) acc = fmaf(g[u], __int_as_float(e[u].y), acc);
  }
  for (; j < cnt; ++j) {
    int2 e = sedge[base + j];
    acc = fmaf(b2f(ego[e.x * RD + i64 + lane]), __int_as_float(e.y), acc);
  }
  prop[n * RD + i64 + lane] = __float2bfloat16(acc);
}

__device__ __forceinline__ float attn_row(float a, float b, float c,
                                          float e0, float e1, float e2) {
  float m = fmaxf(a, fmaxf(b, c));
  float w0 = __expf(a - m), w1 = __expf(b - m), w2 = __expf(c - m);
  float inv = 1.f / (w0 + w1 + w2);
  return (w0 * e0 + w1 * e1 + w2 * e2) * inv;
}

// MFMA transform: X(300000x64) @ W(64x64), X = prop * rela (per-relation).
// Block = 64 nodes = 192 X-rows. Wave w owns W cols [16w,16w+16).
// 12 row-tiles x 2 mfma_16x16x32_bf16. est -> LDS (stride 66) -> 3x3 attn.
__global__ __launch_bounds__(256) void transform_attn_kernel(
    const bf16* __restrict__ prop, const float* __restrict__ rela_k,
    const void* __restrict__ Wgc, int wgc_off, const int* __restrict__ flag,
    bf16* __restrict__ ego_out) {
  bool f32 = *flag != 0;
  __shared__ float est_s[192 * 66];
  int t = threadIdx.x, lane = t & 63, wave = t >> 6;
  int quad = lane >> 4, m = lane & 15;
  int wcol = wave * 16 + m;   // this lane's D column (global 0..63)
  // B fragments (one-time): B[k=quad*8+j][n=wcol]
  short8 b0, b1;
#pragma unroll
  for (int j = 0; j < 8; ++j) {
    int k0 = quad * 8 + j;
    b0[j] = (short)f2bits(loadf(Wgc, wgc_off + k0 * 64 + wcol, f32));
    b1[j] = (short)f2bits(loadf(Wgc, wgc_off + (k0 + 32) * 64 + wcol, f32));
  }
  // rela values at this lane's k positions, for all 3 relations
  float relv0[16], relv1[16], relv2[16];
#pragma unroll
  for (int j = 0; j < 8; ++j) {
    int k0 = quad * 8 + j;
    relv0[j] = rela_k[k0];        relv0[8 + j] = rela_k[32 + k0];
    relv1[j] = rela_k[64 + k0];   relv1[8 + j] = rela_k[96 + k0];
    relv2[j] = rela_k[128 + k0];  relv2[8 + j] = rela_k[160 + k0];
  }
  int n0 = blockIdx.x * 64;
  int row0 = n0 * 3;
#pragma unroll
  for (int tr = 0; tr < 12; ++tr) {
    int rl = tr * 16 + m;            // local A row
    int row = row0 + rl;
    int row_c = row < M3 ? row : 0;
    int i = rl % 3;                  // relation of this row (row0 % 3 == 0)
    const ushort8* pp = (const ushort8*)(prop + (size_t)row_c * 64 + quad * 8);
    ushort8 x0 = pp[0];              // k = quad*8 .. +7
    ushort8 x1 = pp[4];              // k+32
    short8 a0, a1;
#pragma unroll
    for (int j = 0; j < 8; ++j) {
      float r0 = (i == 0) ? relv0[j] : (i == 1 ? relv1[j] : relv2[j]);
      float r1 = (i == 0) ? relv0[8 + j] : (i == 1 ? relv1[8 + j] : relv2[8 + j]);
      a0[j] = (short)f2bits(bits2f(x0[j]) * r0);
      a1[j] = (short)f2bits(bits2f(x1[j]) * r1);
    }
    f32x4 acc = {0.f, 0.f, 0.f, 0.f};
    acc = __builtin_amdgcn_mfma_f32_16x16x32_bf16(a0, b0, acc, 0, 0, 0);
    acc = __builtin_amdgcn_mfma_f32_16x16x32_bf16(a1, b1, acc, 0, 0, 0);
#pragma unroll
    for (int r = 0; r < 4; ++r) {
      float v = acc[r];
      v = v > 0.f ? v : 0.01f * v;   // leaky relu
      est_s[(tr * 16 + quad * 4 + r) * 66 + wcol] = v;
    }
  }
  __syncthreads();
  const float sc = 0.088388347648318447f;  // 1/sqrt(128)
  for (int jj = 0; jj < 16; ++jj) {
    int nl = wave * 16 + jj;
    int n = n0 + nl;
    if (n >= N_NODES) break;
    float e0 = est_s[(3 * nl + 0) * 66 + lane];
    float e1 = est_s[(3 * nl + 1) * 66 + lane];
    float e2 = est_s[(3 * nl + 2) * 66 + lane];
    float s00 = wave_sum(e0 * e0);
    float s01 = wave_sum(e0 * e1);
    float s02 = wave_sum(e0 * e2);
    float s11 = wave_sum(e1 * e1);
    float s12 = wave_sum(e1 * e2);
    float s22 = wave_sum(e2 * e2);
    float o0 = attn_row(s00 * sc, s01 * sc, s02 * sc, e0, e1, e2);
    float o1 = attn_row(s01 * sc, s11 * sc, s12 * sc, e0, e1, e2);
    float o2 = attn_row(s02 * sc, s12 * sc, s22 * sc, e0, e1, e2);
    int base = n * RD + lane;
    ego_out[base] = __float2bfloat16(o0);
    ego_out[base + 64] = __float2bfloat16(o1);
    ego_out[base + 128] = __float2bfloat16(o2);
  }
}

// final attention (row 2 only) + outputs; users also do GRU matvecs + scores
__global__ __launch_bounds__(256) void final_kernel(
    const bf16* __restrict__ ego0, const bf16* __restrict__ ego1,
    const bf16* __restrict__ ego2, const void* __restrict__ gru_w,
    const void* __restrict__ gru_b, const void* __restrict__ tra,
    const int* __restrict__ flag, void* out) {
  bool f32 = *flag != 0;
  __shared__ float Wg[3 * 4096];
  __shared__ float bs[192];
  __shared__ float ts[256];
  int t = threadIdx.x, lane = t & 63, wave = t >> 6;
  for (int j = t; j < 12288; j += 256) Wg[j] = loadf(gru_w, j, f32);
  if (t < 192) bs[t] = loadf(gru_b, t, f32);
  ts[t] = loadf(tra, t, f32);
  __syncthreads();
  int n0 = blockIdx.x * 64 + wave * 16;
  for (int jj = 0; jj < 16; ++jj) {
    int n = n0 + jj;
    if (n >= N_NODES) break;
    int b0 = n * RD + lane;
    float a0 = b2f(ego0[b0]) + b2f(ego1[b0]) + b2f(ego2[b0]);
    float a1 = b2f(ego0[b0 + 64]) + b2f(ego1[b0 + 64]) + b2f(ego2[b0 + 64]);
    float a2 = b2f(ego0[b0 + 128]) + b2f(ego1[b0 + 128]) + b2f(ego2[b0 + 128]);
    float s20 = wave_sum(a2 * a0);
    float s21 = wave_sum(a2 * a1);
    float s22 = wave_sum(a2 * a2);
    float mid2 = attn_row(s20, s21, s22, a0, a1, a2);
    float f0 = a0 * (1.f / 3.f), f1 = a1 * (1.f / 3.f), f2 = mid2 * (1.f / 3.f);
    if (n < N_USERS) {
      int ob = OFF_U + n * RD + lane;
      storef(out, ob, f0, f32);
      storef(out, ob + 64, f1, f32);
      storef(out, ob + 128, f2, f32);
      float y0 = bs[lane], y1 = bs[64 + lane], y2 = bs[128 + lane];
#pragma unroll
      for (int d = 0; d < 64; ++d) {
        y0 += __shfl(f0, d, 64) * Wg[d * 64 + lane];
        y1 += __shfl(f1, d, 64) * Wg[4096 + d * 64 + lane];
        y2 += __shfl(f2, d, 64) * Wg[8192 + d * 64 + lane];
      }
      float aux1 = f0 * y0, aux2 = f1 * y1, tgt = f2 * y2;
      float sc1 = wave_sum(tgt * ts[lane] + aux1 * ts[64 + lane]);
      float sc2 = wave_sum(tgt * ts[128 + lane] + aux2 * ts[192 + lane]);
      if (lane == 0) {
        storef(out, OFF_S1 + n, sc1, f32);
        storef(out, OFF_S2 + n, sc2, f32);
      }
    } else {
      int ob = OFF_I + (n - N_USERS) * RD + lane;
      storef(out, ob, f0, f32);
      storef(out, ob + 64, f1, f32);
      storef(out, ob + 128, f2, f32);
    }
  }
}

extern "C" void kernel_launch(void* const* d_in, const int* in_sizes, int n_in,
                              void* d_out, int out_size, void* d_ws,
                              size_t ws_size, hipStream_t stream) {
  const void* user_emb = d_in[0];
  const void* item_emb = d_in[1];
  const void* rel_emb = d_in[2];
  const void* W_gc = d_in[3];
  const void* W_rel = d_in[4];
  const void* gru_w = d_in[5];
  const void* gru_b = d_in[6];
  const void* tra = d_in[7];
  const void* adj_vals = d_in[8];
  const int* adj_rows = (const int*)d_in[9];
  const int* adj_cols = (const int*)d_in[10];

  // ws layout (~156 MB)
  int* flag = (int*)d_ws;
  float* wsf = (float*)d_ws;
  float* rela_f = wsf + 16;                       // 576 floats
  int* counts = (int*)(wsf + 1024);               // 300k
  int* offs = counts + M3;                        // 300k
  int* gcursor = offs + M3;                       // 512
  int* bsums = gcursor + 512;                     // 1024
  int* bsums2 = bsums + 1024;                     // 1024
  u64* abuf = (u64*)(bsums2 + 1024);              // 4.8M u64 (8B-aligned)
  int2* sedge = (int2*)(abuf + NE3);              // 4.8M int2
  bf16* ego0 = (bf16*)(sedge + NE3);              // 19.2M bf16
  bf16* ego1 = ego0 + (size_t)N_NODES * RD;
  bf16* ego2 = ego1 + (size_t)N_NODES * RD;
  bf16* prop = ego2 + (size_t)N_NODES * RD;

  const int nbScan = (M3 + 1023) / 1024;          // 293

  detect_kernel<<<1, 256, 0, stream>>>((const unsigned short*)user_emb, flag);
  rela_kernel<<<1, 192, 0, stream>>>(rel_emb, W_rel, flag, rela_f, d_out);
  zero_row_kernel<<<1, 192, 0, stream>>>(d_out, flag);
  init_kernel<<<(N_NODES * RD + 255) / 256, 256, 0, stream>>>(
      user_emb, item_emb, flag, ego0);

  (void)hipMemsetAsync(counts, 0, (size_t)M3 * sizeof(int), stream);
  hist_kernel<<<(NE3 + 255) / 256, 256, 0, stream>>>(adj_rows, counts);
  scanA_kernel<<<nbScan, 1024, 0, stream>>>(counts, offs, bsums);
  scanB_kernel<<<1, 512, 0, stream>>>(bsums, bsums2, nbScan);
  scanC_kernel<<<nbScan, 1024, 0, stream>>>(offs, bsums2);
  binit_kernel<<<1, 512, 0, stream>>>(offs, gcursor);
  passA_kernel<<<(NE3 + 4095) / 4096, 256, 0, stream>>>(
      adj_rows, adj_cols, adj_vals, flag, gcursor, abuf);
  passB_kernel<<<NBUCK, 256, 0, stream>>>(abuf, offs, sedge);

  gather_kernel<<<M3 / 4, 256, 0, stream>>>(sedge, counts, offs, ego0, prop);
  transform_attn_kernel<<<(N_NODES + 63) / 64, 256, 0, stream>>>(
      prop, rela_f, W_gc, 0, flag, ego1);
  gather_kernel<<<M3 / 4, 256, 0, stream>>>(sedge, counts, offs, ego1, prop);
  transform_attn_kernel<<<(N_NODES + 63) / 64, 256, 0, stream>>>(
      prop, rela_f + 192, W_gc, 4096, flag, ego2);

  final_kernel<<<(N_NODES + 63) / 64, 256, 0, stream>>>(
      ego0, ego1, ego2, gru_w, gru_b, tra, flag, d_out);
}

// Round 8
// 1176.470 us; speedup vs baseline: 3.1990x; 1.1124x over previous
//
#include <hip/hip_runtime.h>
#include <hip/hip_bf16.h>

#define N_USERS 70000
#define N_ITEMS 30000
#define N_NODES 100000
#define RD 192      // R*D
#define EE 1600000
#define NE3 4800000
#define M3 300000   // 3 * N_NODES segments
#define NSUB 98     // ceil(100000/1024) row sub-buckets
#define NBUCK 294   // 3 * NSUB

// output element offsets (dtype-independent)
#define OFF_U    0
#define OFF_I    13440000
#define OFF_IZ   19200000   // zero row (item index 30000)
#define OFF_RELA 19200192
#define OFF_S1   19200384
#define OFF_S2   19270384

typedef __hip_bfloat16 bf16;
typedef unsigned long long u64;
typedef __attribute__((ext_vector_type(8))) short short8;
typedef __attribute__((ext_vector_type(8))) unsigned short ushort8;
typedef __attribute__((ext_vector_type(4))) float f32x4;

__device__ __forceinline__ float b2f(bf16 v) { return __bfloat162float(v); }

union bfbits { bf16 b; unsigned short u; };

__device__ __forceinline__ float bits2f(unsigned short u) {
  bfbits x; x.u = u; return b2f(x.b);
}
__device__ __forceinline__ unsigned short f2bits(float f) {
  bfbits x; x.b = __float2bfloat16(f); return x.u;
}

// dtype-adaptive IO: f32 -> fp32 arrays, else bf16 arrays
__device__ __forceinline__ float loadf(const void* p, int i, bool f32) {
  return f32 ? ((const float*)p)[i] : b2f(((const bf16*)p)[i]);
}
__device__ __forceinline__ void storef(void* p, int i, float v, bool f32) {
  if (f32) ((float*)p)[i] = v;
  else ((bf16*)p)[i] = __float2bfloat16(v);
}

__device__ __forceinline__ float wave_sum(float v) {
#pragma unroll
  for (int off = 32; off >= 1; off >>= 1) v += __shfl_xor(v, off, 64);
  return v;
}

__global__ void detect_kernel(const unsigned short* __restrict__ ue,
                              int* __restrict__ flag) {
  __shared__ int s;
  int t = threadIdx.x;
  if (t == 0) s = 0;
  __syncthreads();
  int big = 0;
  for (int j = t; j < 8192; j += 256) {
    int e = (ue[j] >> 7) & 0xFF;
    if (e >= 127) big = 1;
  }
  if (big) atomicOr(&s, 1);
  __syncthreads();
  if (t == 0) *flag = s;
}

__global__ void zero_row_kernel(void* out, const int* __restrict__ flag) {
  bool f32 = *flag != 0;
  storef(out, OFF_IZ + (int)threadIdx.x, 0.f, f32);  // 192 threads
}

// rela chain: rela0=rel_emb, rela1=rela0@W_rel[0], rela2=rela1@W_rel[1]
__global__ void rela_kernel(const void* __restrict__ rel_emb,
                            const void* __restrict__ W_rel,
                            const int* __restrict__ flag,
                            float* __restrict__ rela_f, void* out) {
  bool f32 = *flag != 0;
  __shared__ float r0s[192], r1s[192];
  int t = threadIdx.x;            // 192 threads
  int i = t >> 6, d = t & 63;
  float r0 = loadf(rel_emb, t, f32);
  r0s[t] = r0;
  __syncthreads();
  float acc = 0.f;
  for (int k = 0; k < 64; ++k)
    acc += r0s[i * 64 + k] * loadf(W_rel, k * 64 + d, f32);
  r1s[t] = acc;
  __syncthreads();
  float acc2 = 0.f;
  for (int k = 0; k < 64; ++k)
    acc2 += r1s[i * 64 + k] * loadf(W_rel, 4096 + k * 64 + d, f32);
  rela_f[t] = r0;
  rela_f[192 + t] = acc;
  rela_f[384 + t] = acc2;
  storef(out, OFF_RELA + t, (r0 + acc + acc2) * (1.f / 3.f), f32);
}

__global__ __launch_bounds__(256) void init_kernel(
    const void* __restrict__ user_emb, const void* __restrict__ item_emb,
    const int* __restrict__ flag, bf16* __restrict__ ego0) {
  bool f32 = *flag != 0;
  int idx = blockIdx.x * 256 + threadIdx.x;
  if (idx >= N_NODES * RD) return;
  int n = idx / RD;
  int rd = idx - n * RD;
  int d = rd & 63;
  float v = (n < N_USERS) ? loadf(user_emb, n * 64 + d, f32)
                          : loadf(item_emb, (n - N_USERS) * 64 + d, f32);
  ego0[idx] = __float2bfloat16(v);
}

// ---- CSR build ----
__global__ __launch_bounds__(256) void hist_kernel(
    const int* __restrict__ rows, int* __restrict__ counts) {
  int idx = blockIdx.x * 256 + threadIdx.x;
  if (idx >= NE3) return;
  int i = idx / EE;
  atomicAdd(counts + i * N_NODES + rows[idx], 1);
}

// block-level exclusive scan (1024/block), writes block totals
__global__ __launch_bounds__(1024) void scanA_kernel(
    const int* __restrict__ counts, int* __restrict__ offs,
    int* __restrict__ bsums) {
  __shared__ int s[1024];
  int t = threadIdx.x;
  int idx = blockIdx.x * 1024 + t;
  int x = (idx < M3) ? counts[idx] : 0;
  s[t] = x;
  __syncthreads();
  for (int off = 1; off < 1024; off <<= 1) {
    int y = (t >= off) ? s[t - off] : 0;
    __syncthreads();
    s[t] += y;
    __syncthreads();
  }
  if (idx < M3) offs[idx] = s[t] - x;
  if (t == 1023) bsums[blockIdx.x] = s[t];
}

__global__ __launch_bounds__(512) void scanB_kernel(
    const int* __restrict__ bsums, int* __restrict__ bsums2, int nb) {
  __shared__ int s[512];
  int t = threadIdx.x;
  int x = (t < nb) ? bsums[t] : 0;
  s[t] = x;
  __syncthreads();
  for (int off = 1; off < 512; off <<= 1) {
    int y = (t >= off) ? s[t - off] : 0;
    __syncthreads();
    s[t] += y;
    __syncthreads();
  }
  if (t < nb) bsums2[t] = s[t] - x;
}

__global__ __launch_bounds__(1024) void scanC_kernel(
    int* __restrict__ offs, const int* __restrict__ bsums2) {
  int idx = blockIdx.x * 1024 + threadIdx.x;
  if (idx >= M3) return;
  offs[idx] += bsums2[blockIdx.x];
}

// bucket base cursors: gcursor[b] = offs[first row of bucket]
__global__ void binit_kernel(const int* __restrict__ offs,
                             int* __restrict__ gcursor) {
  int b = threadIdx.x;   // 512 threads
  if (b >= NBUCK) return;
  int rel = b / NSUB, sub = b - rel * NSUB;
  gcursor[b] = offs[rel * N_NODES + (sub << 10)];
}

// Pass A: bucket edges into 294 (rel, row>>10) buckets; runs are
// block-contiguous -> L2 coalesces lines. Packed u64: rowlo<<48|col<<16|bf16
__global__ __launch_bounds__(256) void passA_kernel(
    const int* __restrict__ rows, const int* __restrict__ cols,
    const void* __restrict__ vals, const int* __restrict__ flag,
    int* __restrict__ gcursor, u64* __restrict__ abuf) {
  bool f32 = *flag != 0;
  __shared__ u64 pk[4096];
  __shared__ unsigned short bk[4096];
  __shared__ int cnt[NBUCK], pos[NBUCK], gbase[NBUCK];
  int t = threadIdx.x;
  for (int j = t; j < NBUCK; j += 256) { cnt[j] = 0; pos[j] = 0; }
  __syncthreads();
  int base = blockIdx.x * 4096;
  int m = min(4096, NE3 - base);
  for (int j = t; j < m; j += 256) {
    int idx = base + j;
    int i = idx / EE;
    int r = rows[idx];
    int c = cols[idx];
    unsigned short vb =
        f32 ? f2bits(((const float*)vals)[idx])
            : ((const unsigned short*)vals)[idx];
    int sub = r >> 10;
    int b = i * NSUB + sub;
    pk[j] = ((u64)(r & 1023) << 48) | ((u64)(unsigned)c << 16) | vb;
    bk[j] = (unsigned short)b;
    atomicAdd(&cnt[b], 1);
  }
  __syncthreads();
  for (int j = t; j < NBUCK; j += 256)
    if (cnt[j] > 0) gbase[j] = atomicAdd(&gcursor[j], cnt[j]);
  __syncthreads();
  for (int j = t; j < m; j += 256) {
    int b = bk[j];
    int p = atomicAdd(&pos[b], 1);
    abuf[gbase[b] + p] = pk[j];
  }
}

// Pass B: one block per bucket; LDS row cursors; dest range ~130KB contiguous
__global__ __launch_bounds__(256) void passB_kernel(
    const u64* __restrict__ abuf, const int* __restrict__ offs,
    int2* __restrict__ sedge) {
  __shared__ int curs[1024];
  int b = blockIdx.x;
  int rel = b / NSUB, sub = b - rel * NSUB;
  int r0 = sub << 10;
  int nr = min(1024, N_NODES - r0);
  int gi = rel * N_NODES + r0;
  int t = threadIdx.x;
  for (int j = t; j < nr; j += 256) curs[j] = offs[gi + j];
  __syncthreads();
  int base = offs[gi];
  int endi = gi + nr;
  int end = (endi < M3) ? offs[endi] : NE3;
  for (int e = base + t; e < end; e += 256) {
    u64 w = abuf[e];
    int rowlo = (int)(w >> 48);
    int c = (int)((w >> 16) & 0x3FFFF);
    float v = bits2f((unsigned short)(w & 0xFFFF));
    int p = atomicAdd(&curs[rowlo], 1);
    int2 eo; eo.x = c; eo.y = __float_as_int(v);
    sedge[p] = eo;
  }
}

// one wave per (node, relation) segment; lane = dim. No atomics.
__global__ __launch_bounds__(256) void gather_kernel(
    const int2* __restrict__ sedge, const int* __restrict__ counts,
    const int* __restrict__ offs, const bf16* __restrict__ ego,
    bf16* __restrict__ prop) {
  int seg = blockIdx.x * 4 + (threadIdx.x >> 6);   // i*N_NODES + n
  int lane = threadIdx.x & 63;
  int i = seg / N_NODES;
  int n = seg - i * N_NODES;
  int base = offs[seg];
  int cnt = counts[seg];
  int i64 = i * 64;
  float acc = 0.f;
  int j = 0;
  for (; j + 8 <= cnt; j += 8) {
    int2 e[8];
#pragma unroll
    for (int u = 0; u < 8; ++u) e[u] = sedge[base + j + u];
    float g[8];
#pragma unroll
    for (int u = 0; u < 8; ++u) g[u] = b2f(ego[e[u].x * RD + i64 + lane]);
#pragma unroll
    for (int u = 0; u < 8; ++u) acc = fmaf(g[u], __int_as_float(e[u].y), acc);
  }
  for (; j < cnt; ++j) {
    int2 e = sedge[base + j];
    acc = fmaf(b2f(ego[e.x * RD + i64 + lane]), __int_as_float(e.y), acc);
  }
  prop[n * RD + i64 + lane] = __float2bfloat16(acc);
}

__device__ __forceinline__ float attn_row(float a, float b, float c,
                                          float e0, float e1, float e2) {
  float m = fmaxf(a, fmaxf(b, c));
  float w0 = __expf(a - m), w1 = __expf(b - m), w2 = __expf(c - m);
  float inv = 1.f / (w0 + w1 + w2);
  return (w0 * e0 + w1 * e1 + w2 * e2) * inv;
}

// MFMA transform: X(300000x64) @ W(64x64), X = prop * rela (per-relation).
// Block = 64 nodes = 192 X-rows. Wave w owns W cols [16w,16w+16).
// 12 row-tiles x 2 mfma_16x16x32_bf16. est -> LDS (stride 66) -> 3x3 attn.
__global__ __launch_bounds__(256) void transform_attn_kernel(
    const bf16* __restrict__ prop, const float* __restrict__ rela_k,
    const void* __restrict__ Wgc, int wgc_off, const int* __restrict__ flag,
    bf16* __restrict__ ego_out) {
  bool f32 = *flag != 0;
  __shared__ float est_s[192 * 66];
  int t = threadIdx.x, lane = t & 63, wave = t >> 6;
  int quad = lane >> 4, m = lane & 15;
  int wcol = wave * 16 + m;   // this lane's D column (global 0..63)
  // B fragments (one-time): B[k=quad*8+j][n=wcol]
  short8 b0, b1;
#pragma unroll
  for (int j = 0; j < 8; ++j) {
    int k0 = quad * 8 + j;
    b0[j] = (short)f2bits(loadf(Wgc, wgc_off + k0 * 64 + wcol, f32));
    b1[j] = (short)f2bits(loadf(Wgc, wgc_off + (k0 + 32) * 64 + wcol, f32));
  }
  // rela values at this lane's k positions, for all 3 relations
  float relv0[16], relv1[16], relv2[16];
#pragma unroll
  for (int j = 0; j < 8; ++j) {
    int k0 = quad * 8 + j;
    relv0[j] = rela_k[k0];        relv0[8 + j] = rela_k[32 + k0];
    relv1[j] = rela_k[64 + k0];   relv1[8 + j] = rela_k[96 + k0];
    relv2[j] = rela_k[128 + k0];  relv2[8 + j] = rela_k[160 + k0];
  }
  int n0 = blockIdx.x * 64;
  int row0 = n0 * 3;
#pragma unroll
  for (int tr = 0; tr < 12; ++tr) {
    int rl = tr * 16 + m;            // local A row
    int row = row0 + rl;
    int row_c = row < M3 ? row : 0;
    int i = rl % 3;                  // relation of this row (row0 % 3 == 0)
    const ushort8* pp = (const ushort8*)(prop + (size_t)row_c * 64 + quad * 8);
    ushort8 x0 = pp[0];              // k = quad*8 .. +7
    ushort8 x1 = pp[4];              // k+32
    short8 a0, a1;
#pragma unroll
    for (int j = 0; j < 8; ++j) {
      float r0 = (i == 0) ? relv0[j] : (i == 1 ? relv1[j] : relv2[j]);
      float r1 = (i == 0) ? relv0[8 + j] : (i == 1 ? relv1[8 + j] : relv2[8 + j]);
      a0[j] = (short)f2bits(bits2f(x0[j]) * r0);
      a1[j] = (short)f2bits(bits2f(x1[j]) * r1);
    }
    f32x4 acc = {0.f, 0.f, 0.f, 0.f};
    acc = __builtin_amdgcn_mfma_f32_16x16x32_bf16(a0, b0, acc, 0, 0, 0);
    acc = __builtin_amdgcn_mfma_f32_16x16x32_bf16(a1, b1, acc, 0, 0, 0);
#pragma unroll
    for (int r = 0; r < 4; ++r) {
      float v = acc[r];
      v = v > 0.f ? v : 0.01f * v;   // leaky relu
      est_s[(tr * 16 + quad * 4 + r) * 66 + wcol] = v;
    }
  }
  __syncthreads();
  const float sc = 0.088388347648318447f;  // 1/sqrt(128)
  for (int jj = 0; jj < 16; ++jj) {
    int nl = wave * 16 + jj;
    int n = n0 + nl;
    if (n >= N_NODES) break;
    float e0 = est_s[(3 * nl + 0) * 66 + lane];
    float e1 = est_s[(3 * nl + 1) * 66 + lane];
    float e2 = est_s[(3 * nl + 2) * 66 + lane];
    float s00 = wave_sum(e0 * e0);
    float s01 = wave_sum(e0 * e1);
    float s02 = wave_sum(e0 * e2);
    float s11 = wave_sum(e1 * e1);
    float s12 = wave_sum(e1 * e2);
    float s22 = wave_sum(e2 * e2);
    float o0 = attn_row(s00 * sc, s01 * sc, s02 * sc, e0, e1, e2);
    float o1 = attn_row(s01 * sc, s11 * sc, s12 * sc, e0, e1, e2);
    float o2 = attn_row(s02 * sc, s12 * sc, s22 * sc, e0, e1, e2);
    int base = n * RD + lane;
    ego_out[base] = __float2bfloat16(o0);
    ego_out[base + 64] = __float2bfloat16(o1);
    ego_out[base + 128] = __float2bfloat16(o2);
  }
}

// final: attention row 2, outputs, and MFMA GRU + scores.
// Block = 64 nodes. fmat row = i*64 + node_local, stride 66.
__global__ __launch_bounds__(256) void final_kernel(
    const bf16* __restrict__ ego0, const bf16* __restrict__ ego1,
    const bf16* __restrict__ ego2, const void* __restrict__ gru_w,
    const void* __restrict__ gru_b, const void* __restrict__ tra,
    const int* __restrict__ flag, void* out) {
  bool f32 = *flag != 0;
  __shared__ float fmat[192 * 66];
  __shared__ float sc_lds[128];   // [64 nodes][2]
  int t = threadIdx.x, lane = t & 63, wave = t >> 6;
  int quad = lane >> 4, m = lane & 15;
  int wcol = wave * 16 + m;
  if (t < 128) sc_lds[t] = 0.f;
  // B-frags for gru_w[0..2]; biases; tra scalars (per-lane)
  short8 bw[3][2];
#pragma unroll
  for (int i = 0; i < 3; ++i)
#pragma unroll
    for (int j = 0; j < 8; ++j) {
      int k0 = quad * 8 + j;
      bw[i][0][j] = (short)f2bits(loadf(gru_w, i * 4096 + k0 * 64 + wcol, f32));
      bw[i][1][j] =
          (short)f2bits(loadf(gru_w, i * 4096 + (k0 + 32) * 64 + wcol, f32));
    }
  float bias0 = loadf(gru_b, wcol, f32);
  float bias1 = loadf(gru_b, 64 + wcol, f32);
  float bias2 = loadf(gru_b, 128 + wcol, f32);
  float ts0 = loadf(tra, wcol, f32);        // tra[0][:64]   (tgt -> sc1)
  float ts1 = loadf(tra, 64 + wcol, f32);   // tra[0][64:]   (aux1 -> sc1)
  float ts2 = loadf(tra, 128 + wcol, f32);  // tra[1][:64]   (tgt -> sc2)
  float ts3 = loadf(tra, 192 + wcol, f32);  // tra[1][64:]   (aux2 -> sc2)

  int n0 = blockIdx.x * 64;
  // Phase 1: attention + u/i outputs + fmat
  for (int jj = 0; jj < 16; ++jj) {
    int nl = wave * 16 + jj;
    int n = n0 + nl;
    float f0 = 0.f, f1 = 0.f, f2 = 0.f;
    if (n < N_NODES) {
      int b0i = n * RD + lane;
      float a0 = b2f(ego0[b0i]) + b2f(ego1[b0i]) + b2f(ego2[b0i]);
      float a1 =
          b2f(ego0[b0i + 64]) + b2f(ego1[b0i + 64]) + b2f(ego2[b0i + 64]);
      float a2 =
          b2f(ego0[b0i + 128]) + b2f(ego1[b0i + 128]) + b2f(ego2[b0i + 128]);
      float s20 = wave_sum(a2 * a0);
      float s21 = wave_sum(a2 * a1);
      float s22 = wave_sum(a2 * a2);
      float mid2 = attn_row(s20, s21, s22, a0, a1, a2);
      f0 = a0 * (1.f / 3.f);
      f1 = a1 * (1.f / 3.f);
      f2 = mid2 * (1.f / 3.f);
      if (n < N_USERS) {
        int ob = OFF_U + n * RD + lane;
        storef(out, ob, f0, f32);
        storef(out, ob + 64, f1, f32);
        storef(out, ob + 128, f2, f32);
      } else {
        int ob = OFF_I + (n - N_USERS) * RD + lane;
        storef(out, ob, f0, f32);
        storef(out, ob + 64, f1, f32);
        storef(out, ob + 128, f2, f32);
      }
    }
    fmat[(0 * 64 + nl) * 66 + lane] = f0;
    fmat[(1 * 64 + nl) * 66 + lane] = f1;
    fmat[(2 * 64 + nl) * 66 + lane] = f2;
  }
  __syncthreads();
  // Phase 2: 3 GEMMs (64x64 @ 64x64) + score partials
#pragma unroll
  for (int i = 0; i < 3; ++i) {
    float bias = (i == 0) ? bias0 : (i == 1 ? bias1 : bias2);
#pragma unroll
    for (int tr = 0; tr < 4; ++tr) {
      int arow = (i * 64 + tr * 16 + m) * 66;
      short8 a0, a1;
#pragma unroll
      for (int j = 0; j < 8; ++j) {
        a0[j] = (short)f2bits(fmat[arow + quad * 8 + j]);
        a1[j] = (short)f2bits(fmat[arow + quad * 8 + j + 32]);
      }
      f32x4 acc = {0.f, 0.f, 0.f, 0.f};
      acc = __builtin_amdgcn_mfma_f32_16x16x32_bf16(a0, bw[i][0], acc, 0, 0, 0);
      acc = __builtin_amdgcn_mfma_f32_16x16x32_bf16(a1, bw[i][1], acc, 0, 0, 0);
#pragma unroll
      for (int r = 0; r < 4; ++r) {
        int nl = tr * 16 + quad * 4 + r;
        float y = acc[r] + bias;
        float f = fmat[(i * 64 + nl) * 66 + wcol];
        float prod = f * y;
        float p1 = 0.f, p2 = 0.f;
        if (i == 0) p1 = prod * ts1;
        else if (i == 1) p2 = prod * ts3;
        else { p1 = prod * ts0; p2 = prod * ts2; }
        // reduce over 16 cols (m-lanes, stays within quad)
#pragma unroll
        for (int off = 1; off < 16; off <<= 1) {
          p1 += __shfl_xor(p1, off, 64);
          p2 += __shfl_xor(p2, off, 64);
        }
        if (m == 0) {
          if (i != 1) atomicAdd(&sc_lds[nl * 2], p1);
          if (i != 0) atomicAdd(&sc_lds[nl * 2 + 1], p2);
        }
      }
    }
  }
  __syncthreads();
  // Phase 3: score outputs
  if (t < 64) {
    int n = n0 + t;
    if (n < N_USERS) {
      storef(out, OFF_S1 + n, sc_lds[t * 2], f32);
      storef(out, OFF_S2 + n, sc_lds[t * 2 + 1], f32);
    }
  }
}

extern "C" void kernel_launch(void* const* d_in, const int* in_sizes, int n_in,
                              void* d_out, int out_size, void* d_ws,
                              size_t ws_size, hipStream_t stream) {
  const void* user_emb = d_in[0];
  const void* item_emb = d_in[1];
  const void* rel_emb = d_in[2];
  const void* W_gc = d_in[3];
  const void* W_rel = d_in[4];
  const void* gru_w = d_in[5];
  const void* gru_b = d_in[6];
  const void* tra = d_in[7];
  const void* adj_vals = d_in[8];
  const int* adj_rows = (const int*)d_in[9];
  const int* adj_cols = (const int*)d_in[10];

  // ws layout (~156 MB)
  int* flag = (int*)d_ws;
  float* wsf = (float*)d_ws;
  float* rela_f = wsf + 16;                       // 576 floats
  int* counts = (int*)(wsf + 1024);               // 300k
  int* offs = counts + M3;                        // 300k
  int* gcursor = offs + M3;                       // 512
  int* bsums = gcursor + 512;                     // 1024
  int* bsums2 = bsums + 1024;                     // 1024
  u64* abuf = (u64*)(bsums2 + 1024);              // 4.8M u64 (8B-aligned)
  int2* sedge = (int2*)(abuf + NE3);              // 4.8M int2
  bf16* ego0 = (bf16*)(sedge + NE3);              // 19.2M bf16
  bf16* ego1 = ego0 + (size_t)N_NODES * RD;
  bf16* ego2 = ego1 + (size_t)N_NODES * RD;
  bf16* prop = ego2 + (size_t)N_NODES * RD;

  const int nbScan = (M3 + 1023) / 1024;          // 293

  detect_kernel<<<1, 256, 0, stream>>>((const unsigned short*)user_emb, flag);
  rela_kernel<<<1, 192, 0, stream>>>(rel_emb, W_rel, flag, rela_f, d_out);
  zero_row_kernel<<<1, 192, 0, stream>>>(d_out, flag);
  init_kernel<<<(N_NODES * RD + 255) / 256, 256, 0, stream>>>(
      user_emb, item_emb, flag, ego0);

  (void)hipMemsetAsync(counts, 0, (size_t)M3 * sizeof(int), stream);
  hist_kernel<<<(NE3 + 255) / 256, 256, 0, stream>>>(adj_rows, counts);
  scanA_kernel<<<nbScan, 1024, 0, stream>>>(counts, offs, bsums);
  scanB_kernel<<<1, 512, 0, stream>>>(bsums, bsums2, nbScan);
  scanC_kernel<<<nbScan, 1024, 0, stream>>>(offs, bsums2);
  binit_kernel<<<1, 512, 0, stream>>>(offs, gcursor);
  passA_kernel<<<(NE3 + 4095) / 4096, 256, 0, stream>>>(
      adj_rows, adj_cols, adj_vals, flag, gcursor, abuf);
  passB_kernel<<<NBUCK, 256, 0, stream>>>(abuf, offs, sedge);

  gather_kernel<<<M3 / 4, 256, 0, stream>>>(sedge, counts, offs, ego0, prop);
  transform_attn_kernel<<<(N_NODES + 63) / 64, 256, 0, stream>>>(
      prop, rela_f, W_gc, 0, flag, ego1);
  gather_kernel<<<M3 / 4, 256, 0, stream>>>(sedge, counts, offs, ego1, prop);
  transform_attn_kernel<<<(N_NODES + 63) / 64, 256, 0, stream>>>(
      prop, rela_f + 192, W_gc, 4096, flag, ego2);

  final_kernel<<<(N_NODES + 63) / 64, 256, 0, stream>>>(
      ego0, ego1, ego2, gru_w, gru_b, tra, flag, d_out);
}